// Round 1
// baseline (8522.058 us; speedup 1.0000x reference)
//
#include <hip/hip_runtime.h>
#include <hip/hip_bf16.h>
#include <cstdint>
#include <cstddef>

#define B_ 32
#define S_ 128
#define T_ 128
#define E_ 128
#define U_ 256
#define V_ 32000
#define G4 1024          // 4*U
#define TV 4096000       // T_*V_

typedef __attribute__((ext_vector_type(8))) short short8_t;   // 8 bf16
typedef __attribute__((ext_vector_type(4))) float f32x4;

static __device__ __forceinline__ unsigned short f2bf(float x) {
  union { float f; unsigned int u; } v; v.f = x;
  unsigned int r = (v.u + 0x7fffu + ((v.u >> 16) & 1u)) >> 16;
  return (unsigned short)r;
}
static __device__ __forceinline__ float sigmoidf_(float x) {
  return 1.0f / (1.0f + __expf(-x));
}

// ---------------------------------------------------------------------------
// K1: embedding gather + x@Wx + bias precompute for encoder and decoder.
// 1024 WGs x 256 threads; 8 rows per WG (512 enc WGs, 512 dec WGs).
// ---------------------------------------------------------------------------
__global__ __launch_bounds__(256) void k_prep_x(
    const int* __restrict__ src, const int* __restrict__ tgt,
    const float* __restrict__ enc_emb, const float* __restrict__ enc_Wx,
    const float* __restrict__ enc_b,
    const float* __restrict__ dec_emb, const float* __restrict__ dec_Wx,
    const float* __restrict__ dec_b,
    float* __restrict__ Xe, float* __restrict__ Xd)
{
  __shared__ float emb_l[8][E_];
  int wg = blockIdx.x;
  int tid = threadIdx.x;
  bool is_dec = (wg >= 512);
  int r0 = (is_dec ? (wg - 512) : wg) * 8;
  const float* emb  = is_dec ? dec_emb : enc_emb;
  const float* W    = is_dec ? (dec_Wx + (size_t)U_ * G4) : enc_Wx; // dec: emb rows 256..383
  const float* bias = is_dec ? dec_b : enc_b;
  float* Xout = is_dec ? Xd : Xe;

  // stage 8 embedding rows (8*128 floats)
  for (int i = 0; i < 4; ++i) {
    int lin = i * 256 + tid;
    int rr = lin >> 7, k = lin & 127;
    int r = r0 + rr;               // r = step*32 + b
    int b = r & 31, st = r >> 5;
    int tok;
    if (is_dec) tok = tgt[b * T_ + (st > 0 ? st - 1 : 0)];
    else        tok = src[b * S_ + st];
    emb_l[rr][k] = emb[(size_t)tok * E_ + k];
  }
  __syncthreads();

  float acc[8][4];
  #pragma unroll
  for (int rr = 0; rr < 8; ++rr)
    #pragma unroll
    for (int cc = 0; cc < 4; ++cc) acc[rr][cc] = 0.f;

  for (int k = 0; k < E_; ++k) {
    float w0 = W[(size_t)k * G4 + tid];
    float w1 = W[(size_t)k * G4 + tid + 256];
    float w2 = W[(size_t)k * G4 + tid + 512];
    float w3 = W[(size_t)k * G4 + tid + 768];
    #pragma unroll
    for (int rr = 0; rr < 8; ++rr) {
      float e = emb_l[rr][k];
      acc[rr][0] += e * w0; acc[rr][1] += e * w1;
      acc[rr][2] += e * w2; acc[rr][3] += e * w3;
    }
  }
  #pragma unroll
  for (int rr = 0; rr < 8; ++rr) {
    int r = r0 + rr;
    #pragma unroll
    for (int cc = 0; cc < 4; ++cc) {
      int col = tid + cc * 256;
      Xout[(size_t)r * G4 + col] = acc[rr][cc] + bias[col];
    }
  }
}

// ---------------------------------------------------------------------------
// K2: transpose fc_W [256][32000] f32 -> fcWt [32000][256] bf16
// ---------------------------------------------------------------------------
__global__ __launch_bounds__(256) void k_prep_fcw(
    const float* __restrict__ fcW, unsigned short* __restrict__ fcWt)
{
  __shared__ float tile[64][65];
  int bid = blockIdx.x, tid = threadIdx.x;
  int n0 = (bid % 500) * 64, k0 = (bid / 500) * 64;
  for (int i = 0; i < 16; ++i) {
    int lin = i * 256 + tid;
    int k = lin >> 6, n = lin & 63;
    tile[k][n] = fcW[(size_t)(k0 + k) * V_ + n0 + n];
  }
  __syncthreads();
  for (int i = 0; i < 16; ++i) {
    int lin = i * 256 + tid;
    int n = lin >> 6, k = lin & 63;
    fcWt[(size_t)(n0 + n) * 256 + k0 + k] = f2bf(tile[k][n]);
  }
}

// ---------------------------------------------------------------------------
// K3: encoder LSTM. One WG per batch element, 1024 threads, 128 steps.
// ---------------------------------------------------------------------------
__global__ __launch_bounds__(1024) void k_encoder(
    const float* __restrict__ Xe, const float* __restrict__ Wh,
    float* __restrict__ enc_out, float* __restrict__ h_state,
    float* __restrict__ c_state)
{
  __shared__ float h_l[U_], c_l[U_], z_l[G4];
  int b = blockIdx.x, j = threadIdx.x;
  if (j < U_) { h_l[j] = 0.f; c_l[j] = 0.f; }
  __syncthreads();
  for (int s = 0; s < S_; ++s) {
    float zv = Xe[((size_t)(s * B_ + b)) * G4 + j];
    const float* wc = Wh + j;
    #pragma unroll 4
    for (int k = 0; k < U_; ++k) zv += h_l[k] * wc[(size_t)k * G4];
    z_l[j] = zv;
    __syncthreads();
    if (j < U_) {
      float iv = sigmoidf_(z_l[j]);
      float fv = sigmoidf_(z_l[j + U_]);
      float gv = tanhf(z_l[j + 2 * U_]);
      float ov = sigmoidf_(z_l[j + 3 * U_]);
      float c = fv * c_l[j] + iv * gv;
      c_l[j] = c;
      float h = ov * tanhf(c);
      h_l[j] = h;
      enc_out[((size_t)(b * S_ + s)) * U_ + j] = h;
    }
    __syncthreads();
  }
  if (j < U_) { h_state[b * U_ + j] = h_l[j]; c_state[b * U_ + j] = c_l[j]; }
}

// ---------------------------------------------------------------------------
// K4: keys = enc_out @ att_W2 + b2.  512 WGs x 256 thr, 8 rows each.
// ---------------------------------------------------------------------------
__global__ __launch_bounds__(256) void k_keys(
    const float* __restrict__ enc_out, const float* __restrict__ W2,
    const float* __restrict__ b2, float* __restrict__ keys)
{
  __shared__ float x_l[8][U_];
  int wg = blockIdx.x, tid = threadIdx.x;
  int r0 = wg * 8;
  for (int i = 0; i < 8; ++i) x_l[i][tid] = enc_out[(size_t)(r0 + i) * U_ + tid];
  __syncthreads();
  float acc[8];
  #pragma unroll
  for (int rr = 0; rr < 8; ++rr) acc[rr] = 0.f;
  for (int k = 0; k < U_; ++k) {
    float w = W2[(size_t)k * U_ + tid];
    #pragma unroll
    for (int rr = 0; rr < 8; ++rr) acc[rr] += x_l[rr][k] * w;
  }
  float bb = b2[tid];
  #pragma unroll
  for (int rr = 0; rr < 8; ++rr)
    keys[(size_t)(r0 + rr) * U_ + tid] = acc[rr] + bb;
}

// ---------------------------------------------------------------------------
// K5: decoder with attention. One WG per batch element, 1024 thr, 128 steps.
// ---------------------------------------------------------------------------
__global__ __launch_bounds__(1024) void k_decoder(
    const float* __restrict__ Xd, const float* __restrict__ dec_Wx,
    const float* __restrict__ Wh,
    const float* __restrict__ W1, const float* __restrict__ b1,
    const float* __restrict__ attV, const float* __restrict__ attbV,
    const float* __restrict__ enc_out, const float* __restrict__ keys,
    const float* __restrict__ h0, const float* __restrict__ c0,
    unsigned short* __restrict__ Hbf)
{
  __shared__ float h_l[U_], c_l[U_], q_l[U_], ctx_l[U_], z_l[G4];
  __shared__ float esc[S_];
  __shared__ float part4[4][U_];
  __shared__ float dinv_l;
  int b = blockIdx.x, j = threadIdx.x;
  if (j < U_) { h_l[j] = h0[b * U_ + j]; c_l[j] = c0[b * U_ + j]; }
  float bV = attbV[0];
  const float* eo = enc_out + (size_t)b * S_ * U_;
  const float* ky = keys + (size_t)b * S_ * U_;
  __syncthreads();

  for (int t = 0; t < T_; ++t) {
    // --- q = h @ W1 + b1 (4 partial k-ranges) ---
    {
      int part = j >> 8, col = j & 255;
      float a = 0.f;
      int k0 = part * 64;
      #pragma unroll 4
      for (int k = k0; k < k0 + 64; ++k) a += h_l[k] * W1[(size_t)k * U_ + col];
      part4[part][col] = a;
    }
    __syncthreads();
    if (j < U_) q_l[j] = part4[0][j] + part4[1][j] + part4[2][j] + part4[3][j] + b1[j];
    __syncthreads();

    // --- scores: 8 lanes per s, 32 u each ---
    {
      int sIdx = j >> 3, part = j & 7;
      const float* kr = ky + (size_t)sIdx * U_ + part * 32;
      float a = 0.f;
      #pragma unroll 4
      for (int u = 0; u < 32; ++u)
        a += tanhf(q_l[part * 32 + u] + kr[u]) * attV[part * 32 + u];
      a += __shfl_xor(a, 1); a += __shfl_xor(a, 2); a += __shfl_xor(a, 4);
      if (part == 0) esc[sIdx] = __expf(a + bV);
    }
    __syncthreads();

    // --- softmax denominator (no max-shift: |score| ~ 1e-3) ---
    if (j < 64) {
      float e = esc[j] + esc[j + 64];
      e += __shfl_xor(e, 1); e += __shfl_xor(e, 2); e += __shfl_xor(e, 4);
      e += __shfl_xor(e, 8); e += __shfl_xor(e, 16); e += __shfl_xor(e, 32);
      if (j == 0) dinv_l = 1.0f / e;
    }
    __syncthreads();

    // --- ctx = (sum_s esc*enc_out) * dinv ---
    {
      int grp = j >> 8, u = j & 255;
      float a = 0.f;
      int s0 = grp * 32;
      #pragma unroll 4
      for (int s = s0; s < s0 + 32; ++s) a += esc[s] * eo[(size_t)s * U_ + u];
      part4[grp][u] = a;
    }
    __syncthreads();
    if (j < U_) ctx_l[j] = (part4[0][j] + part4[1][j] + part4[2][j] + part4[3][j]) * dinv_l;
    __syncthreads();

    // --- z = Xd + ctx@Wx_ctx + h@Wh ---
    {
      float zv = Xd[((size_t)(t * B_ + b)) * G4 + j];
      const float* wxc = dec_Wx + j;   // rows 0..255 = ctx rows
      const float* wh  = Wh + j;
      #pragma unroll 4
      for (int k = 0; k < U_; ++k) {
        zv += ctx_l[k] * wxc[(size_t)k * G4];
        zv += h_l[k]  * wh[(size_t)k * G4];
      }
      z_l[j] = zv;
    }
    __syncthreads();

    // --- LSTM pointwise update; store h as bf16 row (t*32+b) ---
    if (j < U_) {
      float iv = sigmoidf_(z_l[j]);
      float fv = sigmoidf_(z_l[j + U_]);
      float gv = tanhf(z_l[j + 2 * U_]);
      float ov = sigmoidf_(z_l[j + 3 * U_]);
      float c = fv * c_l[j] + iv * gv;
      c_l[j] = c;
      float h = ov * tanhf(c);
      h_l[j] = h;
      Hbf[((size_t)(t * B_ + b)) * U_ + j] = f2bf(h);
    }
    __syncthreads();
  }
}

// ---------------------------------------------------------------------------
// K6: fc GEMM (MFMA bf16) + exp epilogue + row-sum partials.
// C = H[4096,256] @ fcW[256,32000]; tiles 128x128, K=256, 256 thr (4 waves).
// ---------------------------------------------------------------------------
__global__ __launch_bounds__(256) void k_fc(
    const unsigned short* __restrict__ Hbf, const unsigned short* __restrict__ fcWt,
    const float* __restrict__ fcb, float* __restrict__ out,
    float* __restrict__ rs_part)
{
  __shared__ uint4 Al[128 * 8];   // A[128][64] bf16, 16B units, XOR-swizzled
  __shared__ uint4 Bl[128 * 8];
  __shared__ float rsum_l[128][2];

  int bid = blockIdx.x, tid = threadIdx.x;
  int nt = bid % 250, mt = bid / 250;
  int m0 = mt * 128, n0 = nt * 128;
  int lane = tid & 63, wave = tid >> 6;
  int wm = (wave >> 1) * 64, wn = (wave & 1) * 64;
  int g = lane >> 4, r15 = lane & 15;

  f32x4 acc[4][4];
  f32x4 zero = {0.f, 0.f, 0.f, 0.f};
  #pragma unroll
  for (int mi = 0; mi < 4; ++mi)
    #pragma unroll
    for (int ni = 0; ni < 4; ++ni) acc[mi][ni] = zero;

  const unsigned short* Ag = Hbf  + (size_t)m0 * 256;
  const unsigned short* Bg = fcWt + (size_t)n0 * 256;

  for (int kt = 0; kt < 4; ++kt) {
    int kk = kt * 64;
    #pragma unroll
    for (int blk = 0; blk < 4; ++blk) {
      int lin = blk * 256 + tid;
      int row = lin >> 3, kq = lin & 7;
      Al[row * 8 + (kq ^ (row & 7))] = *(const uint4*)(Ag + (size_t)row * 256 + kk + kq * 8);
      Bl[row * 8 + (kq ^ (row & 7))] = *(const uint4*)(Bg + (size_t)row * 256 + kk + kq * 8);
    }
    __syncthreads();
    #pragma unroll
    for (int kk2 = 0; kk2 < 2; ++kk2) {
      short8_t a[4], bfr[4];
      #pragma unroll
      for (int mi = 0; mi < 4; ++mi) {
        int row = wm + mi * 16 + r15;
        a[mi] = *(const short8_t*)&Al[row * 8 + ((kk2 * 4 + g) ^ (row & 7))];
      }
      #pragma unroll
      for (int ni = 0; ni < 4; ++ni) {
        int row = wn + ni * 16 + r15;
        bfr[ni] = *(const short8_t*)&Bl[row * 8 + ((kk2 * 4 + g) ^ (row & 7))];
      }
      #pragma unroll
      for (int mi = 0; mi < 4; ++mi)
        #pragma unroll
        for (int ni = 0; ni < 4; ++ni)
          acc[mi][ni] = __builtin_amdgcn_mfma_f32_16x16x32_bf16(a[mi], bfr[ni], acc[mi][ni], 0, 0, 0);
    }
    __syncthreads();
  }

  // epilogue: exp(logit + fc_b), scatter to out[b][t][v], per-row partial sums
  float fcb_l[4];
  #pragma unroll
  for (int ni = 0; ni < 4; ++ni) fcb_l[ni] = fcb[n0 + wn + ni * 16 + r15];

  #pragma unroll
  for (int mi = 0; mi < 4; ++mi) {
    #pragma unroll
    for (int jj = 0; jj < 4; ++jj) {
      int rloc = wm + mi * 16 + g * 4 + jj;     // 0..127 within tile
      int grow = m0 + rloc;                     // = t*32 + b
      int bb = grow & 31, tt = grow >> 5;
      size_t obase = (size_t)bb * TV + (size_t)tt * V_;
      float s = 0.f;
      #pragma unroll
      for (int ni = 0; ni < 4; ++ni) {
        float v = __expf(acc[mi][ni][jj] + fcb_l[ni]);
        out[obase + n0 + wn + ni * 16 + r15] = v;
        s += v;
      }
      s += __shfl_xor(s, 1); s += __shfl_xor(s, 2);
      s += __shfl_xor(s, 4); s += __shfl_xor(s, 8);
      if (r15 == 0) rsum_l[rloc][wave & 1] = s;
    }
  }
  __syncthreads();
  if (tid < 128)
    rs_part[(size_t)nt * 4096 + m0 + tid] = rsum_l[tid][0] + rsum_l[tid][1];
}

// ---------------------------------------------------------------------------
// K7: reduce partial row sums -> 1/sum per GEMM row
// ---------------------------------------------------------------------------
__global__ __launch_bounds__(256) void k_rowsum(
    const float* __restrict__ rs_part, float* __restrict__ row_inv)
{
  int gidx = blockIdx.x * 256 + threadIdx.x;  // 0..4095
  float s = 0.f;
  for (int nt = 0; nt < 250; ++nt) s += rs_part[(size_t)nt * 4096 + gidx];
  row_inv[gidx] = 1.0f / s;
}

// ---------------------------------------------------------------------------
// K8: normalize probs in place (float4 grid-stride)
// ---------------------------------------------------------------------------
__global__ __launch_bounds__(256) void k_norm(
    float4* __restrict__ out4, const float* __restrict__ row_inv)
{
  const long total = 32768000;  // 131072000/4
  long stride = (long)gridDim.x * 256;
  for (long i = (long)blockIdx.x * 256 + threadIdx.x; i < total; i += stride) {
    long flat = i * 4;
    int bb = (int)(flat / TV);
    int rem = (int)(flat % TV);
    int tt = rem / V_;
    float sc = row_inv[tt * 32 + bb];
    float4 v = out4[i];
    v.x *= sc; v.y *= sc; v.z *= sc; v.w *= sc;
    out4[i] = v;
  }
}

// ---------------------------------------------------------------------------
extern "C" void kernel_launch(void* const* d_in, const int* in_sizes, int n_in,
                              void* d_out, int out_size, void* d_ws, size_t ws_size,
                              hipStream_t stream) {
  (void)in_sizes; (void)n_in; (void)out_size; (void)ws_size;
  const int*   src     = (const int*)d_in[0];
  const int*   tgt     = (const int*)d_in[1];
  const float* enc_emb = (const float*)d_in[2];
  const float* enc_Wx  = (const float*)d_in[3];
  const float* enc_Wh  = (const float*)d_in[4];
  const float* enc_b   = (const float*)d_in[5];
  const float* dec_emb = (const float*)d_in[6];
  const float* dec_Wx  = (const float*)d_in[7];
  const float* dec_Wh  = (const float*)d_in[8];
  const float* dec_b   = (const float*)d_in[9];
  const float* att_W1  = (const float*)d_in[10];
  const float* att_b1  = (const float*)d_in[11];
  const float* att_W2  = (const float*)d_in[12];
  const float* att_b2  = (const float*)d_in[13];
  const float* att_V   = (const float*)d_in[14];
  const float* att_bV  = (const float*)d_in[15];
  const float* fc_W    = (const float*)d_in[16];
  const float* fc_b    = (const float*)d_in[17];
  float* out = (float*)d_out;

  char* ws = (char*)d_ws;
  size_t o = 0;
  auto alloc = [&](size_t bytes) {
    char* p = ws + o;
    o = (o + bytes + 255) & ~(size_t)255;
    return p;
  };
  float*          Xe      = (float*)alloc((size_t)S_ * B_ * G4 * 4);   // 16 MB
  float*          Xd      = (float*)alloc((size_t)T_ * B_ * G4 * 4);   // 16 MB
  float*          enc_out = (float*)alloc((size_t)B_ * S_ * U_ * 4);   //  4 MB
  float*          keys    = (float*)alloc((size_t)B_ * S_ * U_ * 4);   //  4 MB
  unsigned short* Hbf     = (unsigned short*)alloc((size_t)T_ * B_ * U_ * 2); // 2 MB
  unsigned short* fcWt    = (unsigned short*)alloc((size_t)V_ * U_ * 2);      // 16 MB
  float*          h_state = (float*)alloc((size_t)B_ * U_ * 4);
  float*          c_state = (float*)alloc((size_t)B_ * U_ * 4);
  float*          rs_part = (float*)alloc((size_t)250 * 4096 * 4);     //  4 MB
  float*          row_inv = (float*)alloc((size_t)4096 * 4);

  hipLaunchKernelGGL(k_prep_x, dim3(1024), dim3(256), 0, stream,
                     src, tgt, enc_emb, enc_Wx, enc_b, dec_emb, dec_Wx, dec_b, Xe, Xd);
  hipLaunchKernelGGL(k_prep_fcw, dim3(2000), dim3(256), 0, stream, fc_W, fcWt);
  hipLaunchKernelGGL(k_encoder, dim3(32), dim3(1024), 0, stream,
                     Xe, enc_Wh, enc_out, h_state, c_state);
  hipLaunchKernelGGL(k_keys, dim3(512), dim3(256), 0, stream,
                     enc_out, att_W2, att_b2, keys);
  hipLaunchKernelGGL(k_decoder, dim3(32), dim3(1024), 0, stream,
                     Xd, dec_Wx, dec_Wh, att_W1, att_b1, att_V, att_bV,
                     enc_out, keys, h_state, c_state, Hbf);
  hipLaunchKernelGGL(k_fc, dim3(8000), dim3(256), 0, stream,
                     Hbf, fcWt, fc_b, out, rs_part);
  hipLaunchKernelGGL(k_rowsum, dim3(16), dim3(256), 0, stream, rs_part, row_inv);
  hipLaunchKernelGGL(k_norm, dim3(2048), dim3(256), 0, stream,
                     (float4*)d_out, row_inv);
}

// Round 2
// 1855.309 us; speedup vs baseline: 4.5933x; 4.5933x over previous
//
#include <hip/hip_runtime.h>
#include <hip/hip_bf16.h>
#include <cstdint>
#include <cstddef>

#define B_ 32
#define S_ 128
#define T_ 128
#define E_ 128
#define U_ 256
#define V_ 32000
#define G4 1024          // 4*U
#define TV 4096000       // T_*V_

typedef __attribute__((ext_vector_type(8))) short short8_t;   // 8 bf16
typedef __attribute__((ext_vector_type(4))) float f32x4;
typedef unsigned long long u64;

static __device__ __forceinline__ unsigned short f2bf(float x) {
  union { float f; unsigned int u; } v; v.f = x;
  unsigned int r = (v.u + 0x7fffu + ((v.u >> 16) & 1u)) >> 16;
  return (unsigned short)r;
}
static __device__ __forceinline__ unsigned int pack2bf(float a, float b) {
  return (unsigned int)f2bf(a) | ((unsigned int)f2bf(b) << 16);
}
static __device__ __forceinline__ float bf_lo(unsigned int w) { return __uint_as_float(w << 16); }
static __device__ __forceinline__ float bf_hi(unsigned int w) { return __uint_as_float(w & 0xffff0000u); }
static __device__ __forceinline__ float sigmoidf_(float x) {
  return 1.0f / (1.0f + __expf(-x));
}
static __device__ __forceinline__ float tanhf_(float x) {
  float e = __expf(2.0f * x);
  return 1.0f - 2.0f / (e + 1.0f);
}

// ---- tagged agent-scope publication: payload (f32) + step tag in one u64 ----
static __device__ __forceinline__ void pub64(u64* p, float val, unsigned tag) {
  u64 v = ((u64)tag << 32) | (u64)__float_as_uint(val);
  __hip_atomic_store(p, v, __ATOMIC_RELAXED, __HIP_MEMORY_SCOPE_AGENT);
}
static __device__ __forceinline__ u64 ld64(const u64* p) {
  return __hip_atomic_load(p, __ATOMIC_RELAXED, __HIP_MEMORY_SCOPE_AGENT);
}
static __device__ __forceinline__ float sub64(const u64* p, unsigned tag) {
  u64 v = ld64(p);
  while ((unsigned)(v >> 32) < tag) { __builtin_amdgcn_s_sleep(1); v = ld64(p); }
  return __uint_as_float((unsigned)v);
}

// ---------------------------------------------------------------------------
// K1: embedding gather + x@Wx + bias precompute for encoder and decoder.
// ---------------------------------------------------------------------------
__global__ __launch_bounds__(256) void k_prep_x(
    const int* __restrict__ src, const int* __restrict__ tgt,
    const float* __restrict__ enc_emb, const float* __restrict__ enc_Wx,
    const float* __restrict__ enc_b,
    const float* __restrict__ dec_emb, const float* __restrict__ dec_Wx,
    const float* __restrict__ dec_b,
    float* __restrict__ Xe, float* __restrict__ Xd)
{
  __shared__ float emb_l[8][E_];
  int wg = blockIdx.x;
  int tid = threadIdx.x;
  bool is_dec = (wg >= 512);
  int r0 = (is_dec ? (wg - 512) : wg) * 8;
  const float* emb  = is_dec ? dec_emb : enc_emb;
  const float* W    = is_dec ? (dec_Wx + (size_t)U_ * G4) : enc_Wx;
  const float* bias = is_dec ? dec_b : enc_b;
  float* Xout = is_dec ? Xd : Xe;

  for (int i = 0; i < 4; ++i) {
    int lin = i * 256 + tid;
    int rr = lin >> 7, k = lin & 127;
    int r = r0 + rr;               // r = step*32 + b
    int b = r & 31, st = r >> 5;
    int tok;
    if (is_dec) tok = tgt[b * T_ + (st > 0 ? st - 1 : 0)];
    else        tok = src[b * S_ + st];
    emb_l[rr][k] = emb[(size_t)tok * E_ + k];
  }
  __syncthreads();

  float acc[8][4];
  #pragma unroll
  for (int rr = 0; rr < 8; ++rr)
    #pragma unroll
    for (int cc = 0; cc < 4; ++cc) acc[rr][cc] = 0.f;

  for (int k = 0; k < E_; ++k) {
    float w0 = W[(size_t)k * G4 + tid];
    float w1 = W[(size_t)k * G4 + tid + 256];
    float w2 = W[(size_t)k * G4 + tid + 512];
    float w3 = W[(size_t)k * G4 + tid + 768];
    #pragma unroll
    for (int rr = 0; rr < 8; ++rr) {
      float e = emb_l[rr][k];
      acc[rr][0] += e * w0; acc[rr][1] += e * w1;
      acc[rr][2] += e * w2; acc[rr][3] += e * w3;
    }
  }
  #pragma unroll
  for (int rr = 0; rr < 8; ++rr) {
    int r = r0 + rr;
    #pragma unroll
    for (int cc = 0; cc < 4; ++cc) {
      int col = tid + cc * 256;
      Xout[(size_t)r * G4 + col] = acc[rr][cc] + bias[col];
    }
  }
}

// ---------------------------------------------------------------------------
// K2: transpose fc_W [256][32000] f32 -> fcWt [32000][256] bf16
// ---------------------------------------------------------------------------
__global__ __launch_bounds__(256) void k_prep_fcw(
    const float* __restrict__ fcW, unsigned short* __restrict__ fcWt)
{
  __shared__ float tile[64][65];
  int bid = blockIdx.x, tid = threadIdx.x;
  int n0 = (bid % 500) * 64, k0 = (bid / 500) * 64;
  for (int i = 0; i < 16; ++i) {
    int lin = i * 256 + tid;
    int k = lin >> 6, n = lin & 63;
    tile[k][n] = fcW[(size_t)(k0 + k) * V_ + n0 + n];
  }
  __syncthreads();
  for (int i = 0; i < 16; ++i) {
    int lin = i * 256 + tid;
    int n = lin >> 6, k = lin & 63;
    fcWt[(size_t)(n0 + n) * 256 + k0 + k] = f2bf(tile[k][n]);
  }
}

// ---------------------------------------------------------------------------
// K3: encoder LSTM, 8 WGs per batch element (g = bid&7), weights in LDS bf16.
// Per step: spin-gather h (tagged, double-buffered) -> z slice -> pointwise
// -> publish own 32-element h slice.
// ---------------------------------------------------------------------------
__global__ __launch_bounds__(256) void k_encoder8(
    const float* __restrict__ Xe, const float* __restrict__ Wh,
    float* __restrict__ enc_out, float* __restrict__ h_state,
    float* __restrict__ c_state, u64* __restrict__ hpubE /*[2][32][256]*/)
{
  __shared__ unsigned int WhL[128][128];   // [k2][cl] packed bf16 pairs, 64KB
  __shared__ float h_l[256];
  __shared__ float zp[2][128];

  int bid = blockIdx.x, tid = threadIdx.x;
  int g = bid & 7, b = bid >> 3;

  {
    int cl = tid & 127, kh = tid >> 7;
    int q = cl >> 5, r = cl & 31;
    int gc = q * 256 + g * 32 + r;
    for (int k2 = kh; k2 < 128; k2 += 2) {
      float w0 = Wh[(size_t)(2 * k2) * G4 + gc];
      float w1 = Wh[(size_t)(2 * k2 + 1) * G4 + gc];
      WhL[k2][cl] = pack2bf(w0, w1);
    }
  }
  float c_reg = 0.f, h_reg = 0.f;
  __syncthreads();

  for (int s = 0; s < S_; ++s) {
    // gather h (input of step s)
    if (s == 0) {
      h_l[tid] = 0.f;
    } else {
      const u64* p = &hpubE[((size_t)(s & 1) * 32 + b) * 256 + tid];
      u64 v = ld64(p);
      while ((unsigned)(v >> 32) < (unsigned)s) { __builtin_amdgcn_s_sleep(1); v = ld64(p); }
      h_l[tid] = __uint_as_float((unsigned)v);
    }
    __syncthreads();
    // z partial: half 0 -> k in [0,128), half 1 -> k in [128,256)
    {
      int half = tid >> 7, cl = tid & 127;
      int k2b = half * 64;
      float acc = 0.f;
      #pragma unroll 8
      for (int k2 = 0; k2 < 64; ++k2) {
        unsigned int w = WhL[k2b + k2][cl];
        acc += h_l[2 * (k2b + k2)]     * bf_lo(w);
        acc += h_l[2 * (k2b + k2) + 1] * bf_hi(w);
      }
      zp[half][cl] = acc;
    }
    __syncthreads();
    if (tid < 32) {
      int r = tid, gc = g * 32 + r;
      const float* xe = Xe + (size_t)(s * B_ + b) * G4;
      float zi = zp[0][r]      + zp[1][r]      + xe[gc];
      float zf = zp[0][32 + r] + zp[1][32 + r] + xe[256 + gc];
      float zg = zp[0][64 + r] + zp[1][64 + r] + xe[512 + gc];
      float zo = zp[0][96 + r] + zp[1][96 + r] + xe[768 + gc];
      float c = sigmoidf_(zf) * c_reg + sigmoidf_(zi) * tanhf_(zg);
      c_reg = c;
      float h = sigmoidf_(zo) * tanhf_(c);
      h_reg = h;
      enc_out[((size_t)(b * S_ + s)) * U_ + gc] = h;
      pub64(&hpubE[((size_t)((s + 1) & 1) * 32 + b) * 256 + gc], h, (unsigned)(s + 1));
    }
  }
  if (tid < 32) {
    h_state[b * U_ + g * 32 + tid] = h_reg;
    c_state[b * U_ + g * 32 + tid] = c_reg;
  }
}

// ---------------------------------------------------------------------------
// K4: keys = enc_out @ att_W2 + b2.
// ---------------------------------------------------------------------------
__global__ __launch_bounds__(256) void k_keys(
    const float* __restrict__ enc_out, const float* __restrict__ W2,
    const float* __restrict__ b2, float* __restrict__ keys)
{
  __shared__ float x_l[8][U_];
  int wg = blockIdx.x, tid = threadIdx.x;
  int r0 = wg * 8;
  for (int i = 0; i < 8; ++i) x_l[i][tid] = enc_out[(size_t)(r0 + i) * U_ + tid];
  __syncthreads();
  float acc[8];
  #pragma unroll
  for (int rr = 0; rr < 8; ++rr) acc[rr] = 0.f;
  for (int k = 0; k < U_; ++k) {
    float w = W2[(size_t)k * U_ + tid];
    #pragma unroll
    for (int rr = 0; rr < 8; ++rr) acc[rr] += x_l[rr][k] * w;
  }
  float bb = b2[tid];
  #pragma unroll
  for (int rr = 0; rr < 8; ++rr)
    keys[(size_t)(r0 + rr) * U_ + tid] = acc[rr] + bb;
}

// ---------------------------------------------------------------------------
// K5: decoder, 8 WGs per batch element, all recurrent weights LDS-resident.
// 2 tagged publication rounds per step:
//   R1: h slice (32) + q k-partial (256)      -> gather full h, full q
//   R2: ctx s-partial (256) + esc sum          -> gather full ctx
// then z slice from LDS weights + pointwise.
// ---------------------------------------------------------------------------
__global__ __launch_bounds__(256) void k_decoder8(
    const float* __restrict__ Xd, const float* __restrict__ dec_Wx,
    const float* __restrict__ Wh,
    const float* __restrict__ W1, const float* __restrict__ b1,
    const float* __restrict__ attV, const float* __restrict__ attbV,
    const float* __restrict__ enc_out, const float* __restrict__ keys,
    const float* __restrict__ h0, const float* __restrict__ c0,
    unsigned short* __restrict__ Hbf,
    u64* __restrict__ hpubD   /*[32][256]*/,
    u64* __restrict__ qpart   /*[32][8][256]*/,
    u64* __restrict__ ctxpart /*[32][8][256]*/,
    u64* __restrict__ escsum8 /*[32][8]*/)
{
  __shared__ unsigned int WxL[128][128];   // dec_Wx ctx rows, packed, 64KB
  __shared__ unsigned int WhL[128][128];   // dec_Wh, packed, 64KB
  __shared__ unsigned int W1L[16][256];    // W1 k-slice rows [32g..32g+32), 16KB
  __shared__ float b1_l[256], attV_l[256], h_l[256], q_l[256], ctx_l[256];
  __shared__ float hsl[32], esc_l[16], esg_l[8];
  __shared__ float zp[2][128];

  int bid = blockIdx.x, tid = threadIdx.x;
  int g = bid & 7, b = bid >> 3;

  // ---- one-time LDS weight load (global f32 -> packed bf16) ----
  {
    int cl = tid & 127, kh = tid >> 7;
    int q = cl >> 5, r = cl & 31;
    int gc = q * 256 + g * 32 + r;
    for (int k2 = kh; k2 < 128; k2 += 2) {
      float a0 = dec_Wx[(size_t)(2 * k2) * G4 + gc];
      float a1 = dec_Wx[(size_t)(2 * k2 + 1) * G4 + gc];
      WxL[k2][cl] = pack2bf(a0, a1);
      float b0 = Wh[(size_t)(2 * k2) * G4 + gc];
      float b1v = Wh[(size_t)(2 * k2 + 1) * G4 + gc];
      WhL[k2][cl] = pack2bf(b0, b1v);
    }
  }
  {
    int u = tid;
    #pragma unroll
    for (int k2 = 0; k2 < 16; ++k2) {
      float w0 = W1[(size_t)(g * 32 + 2 * k2) * U_ + u];
      float w1 = W1[(size_t)(g * 32 + 2 * k2 + 1) * U_ + u];
      W1L[k2][u] = pack2bf(w0, w1);
    }
    b1_l[u] = b1[u];
    attV_l[u] = attV[u];
  }
  float bV = attbV[0];
  float c_reg = 0.f, h_reg = 0.f;
  if (tid < 32) {
    h_reg = h0[b * U_ + g * 32 + tid];
    c_reg = c0[b * U_ + g * 32 + tid];
  }
  __syncthreads();

  for (int t = 0; t < T_; ++t) {
    unsigned tag = (unsigned)(t + 1);
    // ---- R1 publish: own h slice + q k-partial ----
    if (tid < 32) {
      hsl[tid] = h_reg;
      pub64(&hpubD[(size_t)b * 256 + g * 32 + tid], h_reg, tag);
    }
    __syncthreads();
    {
      float qp = 0.f;
      #pragma unroll
      for (int k2 = 0; k2 < 16; ++k2) {
        unsigned int w = W1L[k2][tid];
        qp += hsl[2 * k2] * bf_lo(w) + hsl[2 * k2 + 1] * bf_hi(w);
      }
      pub64(&qpart[((size_t)b * 8 + g) * 256 + tid], qp, tag);
    }
    // ---- R1 gather: full h + full q ----
    {
      u64 vh, vq[8];
      bool ok;
      do {
        vh = ld64(&hpubD[(size_t)b * 256 + tid]);
        #pragma unroll
        for (int gg = 0; gg < 8; ++gg)
          vq[gg] = ld64(&qpart[((size_t)b * 8 + gg) * 256 + tid]);
        ok = ((unsigned)(vh >> 32) >= tag);
        #pragma unroll
        for (int gg = 0; gg < 8; ++gg) ok &= ((unsigned)(vq[gg] >> 32) >= tag);
        if (!ok) __builtin_amdgcn_s_sleep(1);
      } while (!ok);
      h_l[tid] = __uint_as_float((unsigned)vh);
      float q = b1_l[tid];
      #pragma unroll
      for (int gg = 0; gg < 8; ++gg) q += __uint_as_float((unsigned)vq[gg]);
      q_l[tid] = q;
    }
    __syncthreads();
    // ---- R2: scores for own 16 s, esc ----
    {
      int sl = tid >> 4, up = tid & 15;
      const float* kr = keys + ((size_t)b * S_ + g * 16 + sl) * U_ + up * 16;
      float a = 0.f;
      #pragma unroll
      for (int uu = 0; uu < 16; ++uu)
        a += tanhf_(q_l[up * 16 + uu] + kr[uu]) * attV_l[up * 16 + uu];
      a += __shfl_xor(a, 1); a += __shfl_xor(a, 2);
      a += __shfl_xor(a, 4); a += __shfl_xor(a, 8);
      if (up == 0) esc_l[sl] = __expf(a + bV);
    }
    __syncthreads();
    // ---- ctx partial over own s-slice, all u + esc sum; publish ----
    {
      float acc = 0.f;
      const float* eo = enc_out + ((size_t)b * S_ + g * 16) * U_ + tid;
      #pragma unroll
      for (int sl = 0; sl < 16; ++sl) acc += esc_l[sl] * eo[(size_t)sl * U_];
      pub64(&ctxpart[((size_t)b * 8 + g) * 256 + tid], acc, tag);
      if (tid == 0) {
        float es = 0.f;
        #pragma unroll
        for (int sl = 0; sl < 16; ++sl) es += esc_l[sl];
        pub64(&escsum8[(size_t)b * 8 + g], es, tag);
      }
    }
    // ---- R2 gather: full ctx + denominator ----
    if (tid < 8) esg_l[tid] = sub64(&escsum8[(size_t)b * 8 + tid], tag);
    float csum;
    {
      u64 vc[8];
      bool ok;
      do {
        #pragma unroll
        for (int gg = 0; gg < 8; ++gg)
          vc[gg] = ld64(&ctxpart[((size_t)b * 8 + gg) * 256 + tid]);
        ok = true;
        #pragma unroll
        for (int gg = 0; gg < 8; ++gg) ok &= ((unsigned)(vc[gg] >> 32) >= tag);
        if (!ok) __builtin_amdgcn_s_sleep(1);
      } while (!ok);
      csum = 0.f;
      #pragma unroll
      for (int gg = 0; gg < 8; ++gg) csum += __uint_as_float((unsigned)vc[gg]);
    }
    __syncthreads();
    {
      float dinv = 1.f / (esg_l[0] + esg_l[1] + esg_l[2] + esg_l[3] +
                          esg_l[4] + esg_l[5] + esg_l[6] + esg_l[7]);
      ctx_l[tid] = csum * dinv;
    }
    __syncthreads();
    // ---- z slice from LDS weights ----
    {
      int half = tid >> 7, cl = tid & 127;
      float acc = 0.f;
      if (half == 0) {
        #pragma unroll 8
        for (int k2 = 0; k2 < 128; ++k2) {
          unsigned int w = WxL[k2][cl];
          acc += ctx_l[2 * k2] * bf_lo(w) + ctx_l[2 * k2 + 1] * bf_hi(w);
        }
      } else {
        #pragma unroll 8
        for (int k2 = 0; k2 < 128; ++k2) {
          unsigned int w = WhL[k2][cl];
          acc += h_l[2 * k2] * bf_lo(w) + h_l[2 * k2 + 1] * bf_hi(w);
        }
      }
      zp[half][cl] = acc;
    }
    __syncthreads();
    // ---- pointwise LSTM update on own 32 units ----
    if (tid < 32) {
      int r = tid, gc = g * 32 + r;
      const float* xd = Xd + (size_t)(t * B_ + b) * G4;
      float zi = zp[0][r]      + zp[1][r]      + xd[gc];
      float zf = zp[0][32 + r] + zp[1][32 + r] + xd[256 + gc];
      float zg = zp[0][64 + r] + zp[1][64 + r] + xd[512 + gc];
      float zo = zp[0][96 + r] + zp[1][96 + r] + xd[768 + gc];
      float c = sigmoidf_(zf) * c_reg + sigmoidf_(zi) * tanhf_(zg);
      c_reg = c;
      float h = sigmoidf_(zo) * tanhf_(c);
      h_reg = h;
      Hbf[(size_t)(t * B_ + b) * U_ + gc] = f2bf(h);
    }
    __syncthreads();
  }
}

// ---------------------------------------------------------------------------
// K6: fc GEMM (MFMA bf16) + exp epilogue + row-sum partials.
// ---------------------------------------------------------------------------
__global__ __launch_bounds__(256) void k_fc(
    const unsigned short* __restrict__ Hbf, const unsigned short* __restrict__ fcWt,
    const float* __restrict__ fcb, float* __restrict__ out,
    float* __restrict__ rs_part)
{
  __shared__ uint4 Al[128 * 8];
  __shared__ uint4 Bl[128 * 8];
  __shared__ float rsum_l[128][2];

  int bid = blockIdx.x, tid = threadIdx.x;
  int nt = bid % 250, mt = bid / 250;
  int m0 = mt * 128, n0 = nt * 128;
  int lane = tid & 63, wave = tid >> 6;
  int wm = (wave >> 1) * 64, wn = (wave & 1) * 64;
  int g = lane >> 4, r15 = lane & 15;

  f32x4 acc[4][4];
  f32x4 zero = {0.f, 0.f, 0.f, 0.f};
  #pragma unroll
  for (int mi = 0; mi < 4; ++mi)
    #pragma unroll
    for (int ni = 0; ni < 4; ++ni) acc[mi][ni] = zero;

  const unsigned short* Ag = Hbf  + (size_t)m0 * 256;
  const unsigned short* Bg = fcWt + (size_t)n0 * 256;

  for (int kt = 0; kt < 4; ++kt) {
    int kk = kt * 64;
    #pragma unroll
    for (int blk = 0; blk < 4; ++blk) {
      int lin = blk * 256 + tid;
      int row = lin >> 3, kq = lin & 7;
      Al[row * 8 + (kq ^ (row & 7))] = *(const uint4*)(Ag + (size_t)row * 256 + kk + kq * 8);
      Bl[row * 8 + (kq ^ (row & 7))] = *(const uint4*)(Bg + (size_t)row * 256 + kk + kq * 8);
    }
    __syncthreads();
    #pragma unroll
    for (int kk2 = 0; kk2 < 2; ++kk2) {
      short8_t a[4], bfr[4];
      #pragma unroll
      for (int mi = 0; mi < 4; ++mi) {
        int row = wm + mi * 16 + r15;
        a[mi] = *(const short8_t*)&Al[row * 8 + ((kk2 * 4 + g) ^ (row & 7))];
      }
      #pragma unroll
      for (int ni = 0; ni < 4; ++ni) {
        int row = wn + ni * 16 + r15;
        bfr[ni] = *(const short8_t*)&Bl[row * 8 + ((kk2 * 4 + g) ^ (row & 7))];
      }
      #pragma unroll
      for (int mi = 0; mi < 4; ++mi)
        #pragma unroll
        for (int ni = 0; ni < 4; ++ni)
          acc[mi][ni] = __builtin_amdgcn_mfma_f32_16x16x32_bf16(a[mi], bfr[ni], acc[mi][ni], 0, 0, 0);
    }
    __syncthreads();
  }

  float fcb_l[4];
  #pragma unroll
  for (int ni = 0; ni < 4; ++ni) fcb_l[ni] = fcb[n0 + wn + ni * 16 + r15];

  #pragma unroll
  for (int mi = 0; mi < 4; ++mi) {
    #pragma unroll
    for (int jj = 0; jj < 4; ++jj) {
      int rloc = wm + mi * 16 + g * 4 + jj;
      int grow = m0 + rloc;                     // = t*32 + b
      int bb = grow & 31, tt = grow >> 5;
      size_t obase = (size_t)bb * TV + (size_t)tt * V_;
      float s = 0.f;
      #pragma unroll
      for (int ni = 0; ni < 4; ++ni) {
        float v = __expf(acc[mi][ni][jj] + fcb_l[ni]);
        out[obase + n0 + wn + ni * 16 + r15] = v;
        s += v;
      }
      s += __shfl_xor(s, 1); s += __shfl_xor(s, 2);
      s += __shfl_xor(s, 4); s += __shfl_xor(s, 8);
      if (r15 == 0) rsum_l[rloc][wave & 1] = s;
    }
  }
  __syncthreads();
  if (tid < 128)
    rs_part[(size_t)nt * 4096 + m0 + tid] = rsum_l[tid][0] + rsum_l[tid][1];
}

// ---------------------------------------------------------------------------
// K7: reduce partial row sums -> 1/sum per GEMM row
// ---------------------------------------------------------------------------
__global__ __launch_bounds__(256) void k_rowsum(
    const float* __restrict__ rs_part, float* __restrict__ row_inv)
{
  int gidx = blockIdx.x * 256 + threadIdx.x;
  float s = 0.f;
  for (int nt = 0; nt < 250; ++nt) s += rs_part[(size_t)nt * 4096 + gidx];
  row_inv[gidx] = 1.0f / s;
}

// ---------------------------------------------------------------------------
// K8: normalize probs in place
// ---------------------------------------------------------------------------
__global__ __launch_bounds__(256) void k_norm(
    float4* __restrict__ out4, const float* __restrict__ row_inv)
{
  const long total = 32768000;
  long stride = (long)gridDim.x * 256;
  for (long i = (long)blockIdx.x * 256 + threadIdx.x; i < total; i += stride) {
    long flat = i * 4;
    int bb = (int)(flat / TV);
    int rem = (int)(flat % TV);
    int tt = rem / V_;
    float sc = row_inv[tt * 32 + bb];
    float4 v = out4[i];
    v.x *= sc; v.y *= sc; v.z *= sc; v.w *= sc;
    out4[i] = v;
  }
}

// ---------------------------------------------------------------------------
extern "C" void kernel_launch(void* const* d_in, const int* in_sizes, int n_in,
                              void* d_out, int out_size, void* d_ws, size_t ws_size,
                              hipStream_t stream) {
  (void)in_sizes; (void)n_in; (void)out_size; (void)ws_size;
  const int*   src     = (const int*)d_in[0];
  const int*   tgt     = (const int*)d_in[1];
  const float* enc_emb = (const float*)d_in[2];
  const float* enc_Wx  = (const float*)d_in[3];
  const float* enc_Wh  = (const float*)d_in[4];
  const float* enc_b   = (const float*)d_in[5];
  const float* dec_emb = (const float*)d_in[6];
  const float* dec_Wx  = (const float*)d_in[7];
  const float* dec_Wh  = (const float*)d_in[8];
  const float* dec_b   = (const float*)d_in[9];
  const float* att_W1  = (const float*)d_in[10];
  const float* att_b1  = (const float*)d_in[11];
  const float* att_W2  = (const float*)d_in[12];
  const float* att_b2  = (const float*)d_in[13];
  const float* att_V   = (const float*)d_in[14];
  const float* att_bV  = (const float*)d_in[15];
  const float* fc_W    = (const float*)d_in[16];
  const float* fc_b    = (const float*)d_in[17];
  float* out = (float*)d_out;

  char* ws = (char*)d_ws;
  size_t o = 0;
  auto alloc = [&](size_t bytes) {
    char* p = ws + o;
    o = (o + bytes + 255) & ~(size_t)255;
    return p;
  };
  float*          Xe      = (float*)alloc((size_t)S_ * B_ * G4 * 4);
  float*          Xd      = (float*)alloc((size_t)T_ * B_ * G4 * 4);
  float*          enc_out = (float*)alloc((size_t)B_ * S_ * U_ * 4);
  float*          keys    = (float*)alloc((size_t)B_ * S_ * U_ * 4);
  unsigned short* Hbf     = (unsigned short*)alloc((size_t)T_ * B_ * U_ * 2);
  unsigned short* fcWt    = (unsigned short*)alloc((size_t)V_ * U_ * 2);
  float*          h_state = (float*)alloc((size_t)B_ * U_ * 4);
  float*          c_state = (float*)alloc((size_t)B_ * U_ * 4);
  float*          rs_part = (float*)alloc((size_t)250 * 4096 * 4);
  float*          row_inv = (float*)alloc((size_t)4096 * 4);
  // tagged publication buffers (must be zeroed每 launch for graph replay)
  size_t pub_off = o;
  u64* hpubE   = (u64*)alloc((size_t)2 * 32 * 256 * 8);
  u64* hpubD   = (u64*)alloc((size_t)32 * 256 * 8);
  u64* qpart   = (u64*)alloc((size_t)32 * 8 * 256 * 8);
  u64* ctxpart = (u64*)alloc((size_t)32 * 8 * 256 * 8);
  u64* escsum8 = (u64*)alloc((size_t)32 * 8 * 8);
  size_t pub_bytes = o - pub_off;

  hipMemsetAsync(ws + pub_off, 0, pub_bytes, stream);
  hipLaunchKernelGGL(k_prep_x, dim3(1024), dim3(256), 0, stream,
                     src, tgt, enc_emb, enc_Wx, enc_b, dec_emb, dec_Wx, dec_b, Xe, Xd);
  hipLaunchKernelGGL(k_prep_fcw, dim3(2000), dim3(256), 0, stream, fc_W, fcWt);
  hipLaunchKernelGGL(k_encoder8, dim3(256), dim3(256), 0, stream,
                     Xe, enc_Wh, enc_out, h_state, c_state, hpubE);
  hipLaunchKernelGGL(k_keys, dim3(512), dim3(256), 0, stream,
                     enc_out, att_W2, att_b2, keys);
  hipLaunchKernelGGL(k_decoder8, dim3(256), dim3(256), 0, stream,
                     Xd, dec_Wx, dec_Wh, att_W1, att_b1, att_V, att_bV,
                     enc_out, keys, h_state, c_state, Hbf,
                     hpubD, qpart, ctxpart, escsum8);
  hipLaunchKernelGGL(k_fc, dim3(8000), dim3(256), 0, stream,
                     Hbf, fcWt, fc_b, out, rs_part);
  hipLaunchKernelGGL(k_rowsum, dim3(16), dim3(256), 0, stream, rs_part, row_inv);
  hipLaunchKernelGGL(k_norm, dim3(2048), dim3(256), 0, stream,
                     (float4*)d_out, row_inv);
}

// Round 3
// 1690.176 us; speedup vs baseline: 5.0421x; 1.0977x over previous
//
#include <hip/hip_runtime.h>
#include <hip/hip_bf16.h>
#include <hip/hip_fp16.h>
#include <cstdint>
#include <cstddef>

#define B_ 32
#define S_ 128
#define T_ 128
#define E_ 128
#define U_ 256
#define V_ 32000
#define G4 1024          // 4*U
#define TV 4096000       // T_*V_

typedef __attribute__((ext_vector_type(8))) short short8_t;   // 8 bf16
typedef __attribute__((ext_vector_type(4))) float f32x4;
typedef unsigned long long u64;

static __device__ __forceinline__ unsigned short f2bf(float x) {
  union { float f; unsigned int u; } v; v.f = x;
  unsigned int r = (v.u + 0x7fffu + ((v.u >> 16) & 1u)) >> 16;
  return (unsigned short)r;
}
static __device__ __forceinline__ unsigned int pack2bf(float a, float b) {
  return (unsigned int)f2bf(a) | ((unsigned int)f2bf(b) << 16);
}
static __device__ __forceinline__ float bf_lo(unsigned int w) { return __uint_as_float(w << 16); }
static __device__ __forceinline__ float bf_hi(unsigned int w) { return __uint_as_float(w & 0xffff0000u); }
static __device__ __forceinline__ float sigmoidf_(float x) {
  return 1.0f / (1.0f + __expf(-x));
}
static __device__ __forceinline__ float tanhf_(float x) {
  float e = __expf(2.0f * x);
  return 1.0f - 2.0f / (e + 1.0f);
}

// ---- e5m2 (truncated fp16) encode/decode ----
static __device__ __forceinline__ unsigned int f2e5(float x) {
  __half h = __float2half(x);
  __half_raw hr = *(__half_raw*)&h;
  unsigned int u = hr.x;
  unsigned int r = (u + 0x7Fu + ((u >> 8) & 1u)) >> 8;   // RNE to 8 bits
  return r & 0xFFu;
}
static __device__ __forceinline__ float e5d(unsigned int w, int i) {
  __half_raw hr;
  hr.x = (unsigned short)(((w >> (8 * i)) & 0xFFu) << 8);
  __half hh = *(__half*)&hr;
  return __half2float(hh);
}

// ---- tagged agent-scope publication: payload (f32) + step tag in one u64 ----
static __device__ __forceinline__ void pub64(u64* p, float val, unsigned tag) {
  u64 v = ((u64)tag << 32) | (u64)__float_as_uint(val);
  __hip_atomic_store(p, v, __ATOMIC_RELAXED, __HIP_MEMORY_SCOPE_AGENT);
}
static __device__ __forceinline__ u64 ld64(const u64* p) {
  return __hip_atomic_load(p, __ATOMIC_RELAXED, __HIP_MEMORY_SCOPE_AGENT);
}

// ---------------------------------------------------------------------------
// K1: embedding gather + x@Wx + bias precompute for encoder and decoder.
// ---------------------------------------------------------------------------
__global__ __launch_bounds__(256) void k_prep_x(
    const int* __restrict__ src, const int* __restrict__ tgt,
    const float* __restrict__ enc_emb, const float* __restrict__ enc_Wx,
    const float* __restrict__ enc_b,
    const float* __restrict__ dec_emb, const float* __restrict__ dec_Wx,
    const float* __restrict__ dec_b,
    float* __restrict__ Xe, float* __restrict__ Xd)
{
  __shared__ float emb_l[8][E_];
  int wg = blockIdx.x;
  int tid = threadIdx.x;
  bool is_dec = (wg >= 512);
  int r0 = (is_dec ? (wg - 512) : wg) * 8;
  const float* emb  = is_dec ? dec_emb : enc_emb;
  const float* W    = is_dec ? (dec_Wx + (size_t)U_ * G4) : enc_Wx;
  const float* bias = is_dec ? dec_b : enc_b;
  float* Xout = is_dec ? Xd : Xe;

  for (int i = 0; i < 4; ++i) {
    int lin = i * 256 + tid;
    int rr = lin >> 7, k = lin & 127;
    int r = r0 + rr;               // r = step*32 + b
    int b = r & 31, st = r >> 5;
    int tok;
    if (is_dec) tok = tgt[b * T_ + (st > 0 ? st - 1 : 0)];
    else        tok = src[b * S_ + st];
    emb_l[rr][k] = emb[(size_t)tok * E_ + k];
  }
  __syncthreads();

  float acc[8][4];
  #pragma unroll
  for (int rr = 0; rr < 8; ++rr)
    #pragma unroll
    for (int cc = 0; cc < 4; ++cc) acc[rr][cc] = 0.f;

  for (int k = 0; k < E_; ++k) {
    float w0 = W[(size_t)k * G4 + tid];
    float w1 = W[(size_t)k * G4 + tid + 256];
    float w2 = W[(size_t)k * G4 + tid + 512];
    float w3 = W[(size_t)k * G4 + tid + 768];
    #pragma unroll
    for (int rr = 0; rr < 8; ++rr) {
      float e = emb_l[rr][k];
      acc[rr][0] += e * w0; acc[rr][1] += e * w1;
      acc[rr][2] += e * w2; acc[rr][3] += e * w3;
    }
  }
  #pragma unroll
  for (int rr = 0; rr < 8; ++rr) {
    int r = r0 + rr;
    #pragma unroll
    for (int cc = 0; cc < 4; ++cc) {
      int col = tid + cc * 256;
      Xout[(size_t)r * G4 + col] = acc[rr][cc] + bias[col];
    }
  }
}

// ---------------------------------------------------------------------------
// K2: transpose fc_W [256][32000] f32 -> fcWt [32000][256] bf16
// ---------------------------------------------------------------------------
__global__ __launch_bounds__(256) void k_prep_fcw(
    const float* __restrict__ fcW, unsigned short* __restrict__ fcWt)
{
  __shared__ float tile[64][65];
  int bid = blockIdx.x, tid = threadIdx.x;
  int n0 = (bid % 500) * 64, k0 = (bid / 500) * 64;
  for (int i = 0; i < 16; ++i) {
    int lin = i * 256 + tid;
    int k = lin >> 6, n = lin & 63;
    tile[k][n] = fcW[(size_t)(k0 + k) * V_ + n0 + n];
  }
  __syncthreads();
  for (int i = 0; i < 16; ++i) {
    int lin = i * 256 + tid;
    int n = lin >> 6, k = lin & 63;
    fcWt[(size_t)(n0 + n) * 256 + k0 + k] = f2bf(tile[k][n]);
  }
}

// ---------------------------------------------------------------------------
// K3: encoder LSTM, 8 WGs per batch element (g = bid&7), weights in LDS bf16.
// ---------------------------------------------------------------------------
__global__ __launch_bounds__(256) void k_encoder8(
    const float* __restrict__ Xe, const float* __restrict__ Wh,
    float* __restrict__ enc_out, float* __restrict__ h_state,
    float* __restrict__ c_state, u64* __restrict__ hpubE /*[2][32][256]*/)
{
  __shared__ unsigned int WhL[128][128];   // [k2][cl] packed bf16 pairs, 64KB
  __shared__ float h_l[256];
  __shared__ float zp[2][128];

  int bid = blockIdx.x, tid = threadIdx.x;
  int g = bid & 7, b = bid >> 3;

  {
    int cl = tid & 127, kh = tid >> 7;
    int q = cl >> 5, r = cl & 31;
    int gc = q * 256 + g * 32 + r;
    for (int k2 = kh; k2 < 128; k2 += 2) {
      float w0 = Wh[(size_t)(2 * k2) * G4 + gc];
      float w1 = Wh[(size_t)(2 * k2 + 1) * G4 + gc];
      WhL[k2][cl] = pack2bf(w0, w1);
    }
  }
  float c_reg = 0.f, h_reg = 0.f;
  __syncthreads();

  for (int s = 0; s < S_; ++s) {
    if (s == 0) {
      h_l[tid] = 0.f;
    } else {
      const u64* p = &hpubE[((size_t)(s & 1) * 32 + b) * 256 + tid];
      u64 v = ld64(p);
      while ((unsigned)(v >> 32) < (unsigned)s) { __builtin_amdgcn_s_sleep(1); v = ld64(p); }
      h_l[tid] = __uint_as_float((unsigned)v);
    }
    __syncthreads();
    {
      int half = tid >> 7, cl = tid & 127;
      int k2b = half * 64;
      float acc = 0.f;
      #pragma unroll 8
      for (int k2 = 0; k2 < 64; ++k2) {
        unsigned int w = WhL[k2b + k2][cl];
        acc += h_l[2 * (k2b + k2)]     * bf_lo(w);
        acc += h_l[2 * (k2b + k2) + 1] * bf_hi(w);
      }
      zp[half][cl] = acc;
    }
    __syncthreads();
    if (tid < 32) {
      int r = tid, gc = g * 32 + r;
      const float* xe = Xe + (size_t)(s * B_ + b) * G4;
      float zi = zp[0][r]      + zp[1][r]      + xe[gc];
      float zf = zp[0][32 + r] + zp[1][32 + r] + xe[256 + gc];
      float zg = zp[0][64 + r] + zp[1][64 + r] + xe[512 + gc];
      float zo = zp[0][96 + r] + zp[1][96 + r] + xe[768 + gc];
      float c = sigmoidf_(zf) * c_reg + sigmoidf_(zi) * tanhf_(zg);
      c_reg = c;
      float h = sigmoidf_(zo) * tanhf_(c);
      h_reg = h;
      enc_out[((size_t)(b * S_ + s)) * U_ + gc] = h;
      pub64(&hpubE[((size_t)((s + 1) & 1) * 32 + b) * 256 + gc], h, (unsigned)(s + 1));
    }
  }
  if (tid < 32) {
    h_state[b * U_ + g * 32 + tid] = h_reg;
    c_state[b * U_ + g * 32 + tid] = c_reg;
  }
}

// ---------------------------------------------------------------------------
// K4: keys = enc_out @ att_W2 + b2.
// ---------------------------------------------------------------------------
__global__ __launch_bounds__(256) void k_keys(
    const float* __restrict__ enc_out, const float* __restrict__ W2,
    const float* __restrict__ b2, float* __restrict__ keys)
{
  __shared__ float x_l[8][U_];
  int wg = blockIdx.x, tid = threadIdx.x;
  int r0 = wg * 8;
  for (int i = 0; i < 8; ++i) x_l[i][tid] = enc_out[(size_t)(r0 + i) * U_ + tid];
  __syncthreads();
  float acc[8];
  #pragma unroll
  for (int rr = 0; rr < 8; ++rr) acc[rr] = 0.f;
  for (int k = 0; k < U_; ++k) {
    float w = W2[(size_t)k * U_ + tid];
    #pragma unroll
    for (int rr = 0; rr < 8; ++rr) acc[rr] += x_l[rr][k] * w;
  }
  float bb = b2[tid];
  #pragma unroll
  for (int rr = 0; rr < 8; ++rr)
    keys[(size_t)(r0 + rr) * U_ + tid] = acc[rr] + bb;
}

// ---------------------------------------------------------------------------
// K5 v3: decoder, 8 WGs x 512 threads per batch element, ONE rendezvous/step.
// LDS (e5m2): Wx-slice, Wh-slice, full keys, full enc_out; W1-slice bf16.
// Per step: gather {h, q-partials} -> full attention locally -> z -> pointwise
// -> publish {h', qpart'} (parity double-buffered tagged slots).
// ---------------------------------------------------------------------------
__global__ __launch_bounds__(512) void k_decoder8(
    const float* __restrict__ Xd, const float* __restrict__ dec_Wx,
    const float* __restrict__ Wh,
    const float* __restrict__ W1, const float* __restrict__ b1,
    const float* __restrict__ attV, const float* __restrict__ attbV,
    const float* __restrict__ enc_out, const float* __restrict__ keys,
    const float* __restrict__ h0, const float* __restrict__ c0,
    unsigned short* __restrict__ Hbf,
    u64* __restrict__ hpubD   /*[2][32][256]*/,
    u64* __restrict__ qpartD  /*[2][32][8][256]*/)
{
  __shared__ unsigned int WxU[128 * 65];   // [c][k4] e5m2x4, stride 65
  __shared__ unsigned int WhU[128 * 65];
  __shared__ unsigned int keyU[128 * 65];  // [s][u4] e5m2x4
  __shared__ unsigned int eoU[128 * 65];
  __shared__ unsigned int W1L[16][256];    // bf16 pairs, rows [32g,32g+32)
  __shared__ __align__(16) float h_l[256];
  __shared__ float q_l[256];
  __shared__ __align__(16) float ctx_l[256];
  __shared__ float esc_l[128];
  __shared__ float hsl[32];
  __shared__ float scratch[512];           // ctx partials [2][256] / z partials [4][128]
  __shared__ float b1_l[256], attV_l[256];
  __shared__ float dinv_l;

  int bid = blockIdx.x, tid = threadIdx.x;
  int b = bid & 31, g = bid >> 5;          // 8 WGs of b share one XCD

  // ---- one-time staging ----
  // Wx (ctx rows), Wh -> e5m2 byte-transposed [c][k]
  for (int idx = tid; idx < 256 * 128; idx += 512) {
    int k = idx >> 7, cl = idx & 127;
    int gc = ((cl >> 5) << 8) + g * 32 + (cl & 31);
    float wx = dec_Wx[(size_t)k * G4 + gc];
    float wh = Wh[(size_t)k * G4 + gc];
    ((unsigned char*)WxU)[cl * 260 + k] = (unsigned char)f2e5(wx);
    ((unsigned char*)WhU)[cl * 260 + k] = (unsigned char)f2e5(wh);
  }
  // keys, enc_out -> e5m2 packed [s][u4]
  for (int idx = tid; idx < 128 * 64; idx += 512) {
    int s = idx >> 6, j = idx & 63;
    float4 kv = *(const float4*)(keys    + ((size_t)b * S_ + s) * U_ + j * 4);
    float4 ev = *(const float4*)(enc_out + ((size_t)b * S_ + s) * U_ + j * 4);
    keyU[s * 65 + j] = f2e5(kv.x) | (f2e5(kv.y) << 8) | (f2e5(kv.z) << 16) | (f2e5(kv.w) << 24);
    eoU [s * 65 + j] = f2e5(ev.x) | (f2e5(ev.y) << 8) | (f2e5(ev.z) << 16) | (f2e5(ev.w) << 24);
  }
  if (tid < 256) {
    #pragma unroll
    for (int k2 = 0; k2 < 16; ++k2) {
      float w0 = W1[(size_t)(g * 32 + 2 * k2) * U_ + tid];
      float w1 = W1[(size_t)(g * 32 + 2 * k2 + 1) * U_ + tid];
      W1L[k2][tid] = pack2bf(w0, w1);
    }
    b1_l[tid] = b1[tid];
    attV_l[tid] = attV[tid];
  }
  float bV = attbV[0];
  float c_reg = 0.f, h_reg = 0.f;
  if (tid < 32) {
    h_reg = h0[b * U_ + g * 32 + tid];
    c_reg = c0[b * U_ + g * 32 + tid];
    hsl[tid] = h_reg;
  }
  __syncthreads();

  // initial publish: tag 1, parity 0
  if (tid < 256) {
    float qp = 0.f;
    #pragma unroll
    for (int k2 = 0; k2 < 16; ++k2) {
      unsigned int w = W1L[k2][tid];
      qp = fmaf(hsl[2 * k2], bf_lo(w), qp);
      qp = fmaf(hsl[2 * k2 + 1], bf_hi(w), qp);
    }
    pub64(&qpartD[(((size_t)0 * 32 + b) * 8 + g) * 256 + tid], qp, 1u);
  }
  if (tid < 32)
    pub64(&hpubD[((size_t)0 * 32 + b) * 256 + g * 32 + tid], h_reg, 1u);

  for (int t = 0; t < T_; ++t) {
    unsigned tag = (unsigned)(t + 1);
    int par = t & 1;

    // ---- prefetch Xd for the pointwise tail ----
    float xd0 = 0.f, xd1 = 0.f, xd2 = 0.f, xd3 = 0.f;
    if (tid < 32) {
      const float* xd = Xd + (size_t)(t * B_ + b) * G4;
      int gc = g * 32 + tid;
      xd0 = xd[gc]; xd1 = xd[256 + gc]; xd2 = xd[512 + gc]; xd3 = xd[768 + gc];
    }

    // ---- rendezvous: gather full h + 8 q-partials ----
    if (tid < 256) {
      const u64* hp = &hpubD[((size_t)par * 32 + b) * 256 + tid];
      const u64* qp0 = &qpartD[(((size_t)par * 32 + b) * 8) * 256 + tid];
      u64 vh, vq[8];
      bool ok;
      do {
        vh = ld64(hp);
        #pragma unroll
        for (int gg = 0; gg < 8; ++gg) vq[gg] = ld64(qp0 + (size_t)gg * 256);
        ok = ((unsigned)(vh >> 32) >= tag);
        #pragma unroll
        for (int gg = 0; gg < 8; ++gg) ok &= ((unsigned)(vq[gg] >> 32) >= tag);
        if (!ok) __builtin_amdgcn_s_sleep(1);
      } while (!ok);
      h_l[tid] = __uint_as_float((unsigned)vh);
      float q = b1_l[tid];
      #pragma unroll
      for (int gg = 0; gg < 8; ++gg) q += __uint_as_float((unsigned)vq[gg]);
      q_l[tid] = q;
    }
    __syncthreads();

    // ---- scores: all 128 s locally (s = tid>>2, u-quarter = tid&3) ----
    {
      int s = tid >> 2, uq = tid & 3;
      const unsigned int* kr = &keyU[s * 65 + uq * 16];
      float a = 0.f;
      #pragma unroll
      for (int j = 0; j < 16; ++j) {
        unsigned int w = kr[j];
        int u0 = uq * 64 + j * 4;
        #pragma unroll
        for (int i2 = 0; i2 < 4; ++i2) {
          float x = q_l[u0 + i2] + e5d(w, i2);
          x = fminf(fmaxf(x, -1.0f), 1.0f);
          float x2 = x * x;
          float th = x * (1.0f + x2 * (-0.333333333f + x2 * (0.133333333f + x2 * (-0.053968254f))));
          a = fmaf(th, attV_l[u0 + i2], a);
        }
      }
      a += __shfl_xor(a, 1); a += __shfl_xor(a, 2);
      if (uq == 0) esc_l[s] = __expf(a + bV);
    }
    __syncthreads();

    // ---- denominator + ctx partials over s-halves ----
    if (tid < 64) {
      float e = esc_l[tid] + esc_l[tid + 64];
      e += __shfl_xor(e, 1); e += __shfl_xor(e, 2); e += __shfl_xor(e, 4);
      e += __shfl_xor(e, 8); e += __shfl_xor(e, 16); e += __shfl_xor(e, 32);
      if (tid == 0) dinv_l = 1.0f / e;
    }
    {
      int u = tid & 255, sh = tid >> 8;
      int shift = (u & 3) * 8;
      const unsigned int* ep = &eoU[(sh * 64) * 65 + (u >> 2)];
      float cacc = 0.f;
      #pragma unroll 8
      for (int s2 = 0; s2 < 64; ++s2) {
        unsigned int w = ep[(size_t)s2 * 65];
        __half_raw hr; hr.x = (unsigned short)(((w >> shift) & 0xFFu) << 8);
        cacc = fmaf(__half2float(*(__half*)&hr), esc_l[sh * 64 + s2], cacc);
      }
      scratch[sh * 256 + u] = cacc;
    }
    __syncthreads();
    if (tid < 256) ctx_l[tid] = (scratch[tid] + scratch[256 + tid]) * dinv_l;
    __syncthreads();

    // ---- z: c = tid&127 (4 gates x 32), k-quarter = tid>>7 ----
    {
      int c = tid & 127, kq = tid >> 7;
      const unsigned int* wxp = &WxU[c * 65 + kq * 16];
      const unsigned int* whp = &WhU[c * 65 + kq * 16];
      float zacc = 0.f;
      #pragma unroll
      for (int j = 0; j < 16; ++j) {
        unsigned int wx = wxp[j], wh = whp[j];
        int k0 = kq * 64 + j * 4;
        float4 cv = *(const float4*)&ctx_l[k0];
        float4 hv = *(const float4*)&h_l[k0];
        zacc = fmaf(e5d(wx, 0), cv.x, zacc); zacc = fmaf(e5d(wh, 0), hv.x, zacc);
        zacc = fmaf(e5d(wx, 1), cv.y, zacc); zacc = fmaf(e5d(wh, 1), hv.y, zacc);
        zacc = fmaf(e5d(wx, 2), cv.z, zacc); zacc = fmaf(e5d(wh, 2), hv.z, zacc);
        zacc = fmaf(e5d(wx, 3), cv.w, zacc); zacc = fmaf(e5d(wh, 3), hv.w, zacc);
      }
      scratch[kq * 128 + c] = zacc;
    }
    __syncthreads();

    // ---- pointwise LSTM update on own 32 units ----
    if (tid < 32) {
      int r = tid, gc = g * 32 + r;
      float zi = scratch[r]      + scratch[128 + r]      + scratch[256 + r]      + scratch[384 + r]      + xd0;
      float zf = scratch[32 + r] + scratch[128 + 32 + r] + scratch[256 + 32 + r] + scratch[384 + 32 + r] + xd1;
      float zg = scratch[64 + r] + scratch[128 + 64 + r] + scratch[256 + 64 + r] + scratch[384 + 64 + r] + xd2;
      float zo = scratch[96 + r] + scratch[128 + 96 + r] + scratch[256 + 96 + r] + scratch[384 + 96 + r] + xd3;
      float c = sigmoidf_(zf) * c_reg + sigmoidf_(zi) * tanhf_(zg);
      c_reg = c;
      float h = sigmoidf_(zo) * tanhf_(c);
      h_reg = h;
      hsl[r] = h;
      Hbf[(size_t)(t * B_ + b) * U_ + gc] = f2bf(h);
    }
    __syncthreads();

    // ---- publish h' + qpart' for step t+1 (parity (t+1)&1, tag t+2) ----
    if (t < T_ - 1) {
      int par1 = (t + 1) & 1;
      unsigned tag2 = (unsigned)(t + 2);
      if (tid < 256) {
        float qp = 0.f;
        #pragma unroll
        for (int k2 = 0; k2 < 16; ++k2) {
          unsigned int w = W1L[k2][tid];
          qp = fmaf(hsl[2 * k2], bf_lo(w), qp);
          qp = fmaf(hsl[2 * k2 + 1], bf_hi(w), qp);
        }
        pub64(&qpartD[(((size_t)par1 * 32 + b) * 8 + g) * 256 + tid], qp, tag2);
      }
      if (tid < 32)
        pub64(&hpubD[((size_t)par1 * 32 + b) * 256 + g * 32 + tid], h_reg, tag2);
    }
  }
}

// ---------------------------------------------------------------------------
// K6: fc GEMM (MFMA bf16) + exp epilogue + row-sum partials.
// ---------------------------------------------------------------------------
__global__ __launch_bounds__(256) void k_fc(
    const unsigned short* __restrict__ Hbf, const unsigned short* __restrict__ fcWt,
    const float* __restrict__ fcb, float* __restrict__ out,
    float* __restrict__ rs_part)
{
  __shared__ uint4 Al[128 * 8];
  __shared__ uint4 Bl[128 * 8];
  __shared__ float rsum_l[128][2];

  int bid = blockIdx.x, tid = threadIdx.x;
  int nt = bid % 250, mt = bid / 250;
  int m0 = mt * 128, n0 = nt * 128;
  int lane = tid & 63, wave = tid >> 6;
  int wm = (wave >> 1) * 64, wn = (wave & 1) * 64;
  int g = lane >> 4, r15 = lane & 15;

  f32x4 acc[4][4];
  f32x4 zero = {0.f, 0.f, 0.f, 0.f};
  #pragma unroll
  for (int mi = 0; mi < 4; ++mi)
    #pragma unroll
    for (int ni = 0; ni < 4; ++ni) acc[mi][ni] = zero;

  const unsigned short* Ag = Hbf  + (size_t)m0 * 256;
  const unsigned short* Bg = fcWt + (size_t)n0 * 256;

  for (int kt = 0; kt < 4; ++kt) {
    int kk = kt * 64;
    #pragma unroll
    for (int blk = 0; blk < 4; ++blk) {
      int lin = blk * 256 + tid;
      int row = lin >> 3, kq = lin & 7;
      Al[row * 8 + (kq ^ (row & 7))] = *(const uint4*)(Ag + (size_t)row * 256 + kk + kq * 8);
      Bl[row * 8 + (kq ^ (row & 7))] = *(const uint4*)(Bg + (size_t)row * 256 + kk + kq * 8);
    }
    __syncthreads();
    #pragma unroll
    for (int kk2 = 0; kk2 < 2; ++kk2) {
      short8_t a[4], bfr[4];
      #pragma unroll
      for (int mi = 0; mi < 4; ++mi) {
        int row = wm + mi * 16 + r15;
        a[mi] = *(const short8_t*)&Al[row * 8 + ((kk2 * 4 + g) ^ (row & 7))];
      }
      #pragma unroll
      for (int ni = 0; ni < 4; ++ni) {
        int row = wn + ni * 16 + r15;
        bfr[ni] = *(const short8_t*)&Bl[row * 8 + ((kk2 * 4 + g) ^ (row & 7))];
      }
      #pragma unroll
      for (int mi = 0; mi < 4; ++mi)
        #pragma unroll
        for (int ni = 0; ni < 4; ++ni)
          acc[mi][ni] = __builtin_amdgcn_mfma_f32_16x16x32_bf16(a[mi], bfr[ni], acc[mi][ni], 0, 0, 0);
    }
    __syncthreads();
  }

  float fcb_l[4];
  #pragma unroll
  for (int ni = 0; ni < 4; ++ni) fcb_l[ni] = fcb[n0 + wn + ni * 16 + r15];

  #pragma unroll
  for (int mi = 0; mi < 4; ++mi) {
    #pragma unroll
    for (int jj = 0; jj < 4; ++jj) {
      int rloc = wm + mi * 16 + g * 4 + jj;
      int grow = m0 + rloc;                     // = t*32 + b
      int bb = grow & 31, tt = grow >> 5;
      size_t obase = (size_t)bb * TV + (size_t)tt * V_;
      float s = 0.f;
      #pragma unroll
      for (int ni = 0; ni < 4; ++ni) {
        float v = __expf(acc[mi][ni][jj] + fcb_l[ni]);
        out[obase + n0 + wn + ni * 16 + r15] = v;
        s += v;
      }
      s += __shfl_xor(s, 1); s += __shfl_xor(s, 2);
      s += __shfl_xor(s, 4); s += __shfl_xor(s, 8);
      if (r15 == 0) rsum_l[rloc][wave & 1] = s;
    }
  }
  __syncthreads();
  if (tid < 128)
    rs_part[(size_t)nt * 4096 + m0 + tid] = rsum_l[tid][0] + rsum_l[tid][1];
}

// ---------------------------------------------------------------------------
// K7: reduce partial row sums -> 1/sum per GEMM row
// ---------------------------------------------------------------------------
__global__ __launch_bounds__(256) void k_rowsum(
    const float* __restrict__ rs_part, float* __restrict__ row_inv)
{
  int gidx = blockIdx.x * 256 + threadIdx.x;
  float s = 0.f;
  for (int nt = 0; nt < 250; ++nt) s += rs_part[(size_t)nt * 4096 + gidx];
  row_inv[gidx] = 1.0f / s;
}

// ---------------------------------------------------------------------------
// K8: normalize probs in place
// ---------------------------------------------------------------------------
__global__ __launch_bounds__(256) void k_norm(
    float4* __restrict__ out4, const float* __restrict__ row_inv)
{
  const long total = 32768000;
  long stride = (long)gridDim.x * 256;
  for (long i = (long)blockIdx.x * 256 + threadIdx.x; i < total; i += stride) {
    long flat = i * 4;
    int bb = (int)(flat / TV);
    int rem = (int)(flat % TV);
    int tt = rem / V_;
    float sc = row_inv[tt * 32 + bb];
    float4 v = out4[i];
    v.x *= sc; v.y *= sc; v.z *= sc; v.w *= sc;
    out4[i] = v;
  }
}

// ---------------------------------------------------------------------------
extern "C" void kernel_launch(void* const* d_in, const int* in_sizes, int n_in,
                              void* d_out, int out_size, void* d_ws, size_t ws_size,
                              hipStream_t stream) {
  (void)in_sizes; (void)n_in; (void)out_size; (void)ws_size;
  const int*   src     = (const int*)d_in[0];
  const int*   tgt     = (const int*)d_in[1];
  const float* enc_emb = (const float*)d_in[2];
  const float* enc_Wx  = (const float*)d_in[3];
  const float* enc_Wh  = (const float*)d_in[4];
  const float* enc_b   = (const float*)d_in[5];
  const float* dec_emb = (const float*)d_in[6];
  const float* dec_Wx  = (const float*)d_in[7];
  const float* dec_Wh  = (const float*)d_in[8];
  const float* dec_b   = (const float*)d_in[9];
  const float* att_W1  = (const float*)d_in[10];
  const float* att_b1  = (const float*)d_in[11];
  const float* att_W2  = (const float*)d_in[12];
  const float* att_b2  = (const float*)d_in[13];
  const float* att_V   = (const float*)d_in[14];
  const float* att_bV  = (const float*)d_in[15];
  const float* fc_W    = (const float*)d_in[16];
  const float* fc_b    = (const float*)d_in[17];
  float* out = (float*)d_out;

  char* ws = (char*)d_ws;
  size_t o = 0;
  auto alloc = [&](size_t bytes) {
    char* p = ws + o;
    o = (o + bytes + 255) & ~(size_t)255;
    return p;
  };
  float*          Xe      = (float*)alloc((size_t)S_ * B_ * G4 * 4);
  float*          Xd      = (float*)alloc((size_t)T_ * B_ * G4 * 4);
  float*          enc_out = (float*)alloc((size_t)B_ * S_ * U_ * 4);
  float*          keys    = (float*)alloc((size_t)B_ * S_ * U_ * 4);
  unsigned short* Hbf     = (unsigned short*)alloc((size_t)T_ * B_ * U_ * 2);
  unsigned short* fcWt    = (unsigned short*)alloc((size_t)V_ * U_ * 2);
  float*          h_state = (float*)alloc((size_t)B_ * U_ * 4);
  float*          c_state = (float*)alloc((size_t)B_ * U_ * 4);
  float*          rs_part = (float*)alloc((size_t)250 * 4096 * 4);
  float*          row_inv = (float*)alloc((size_t)4096 * 4);
  // tagged publication buffers (zeroed each launch for graph replay)
  size_t pub_off = o;
  u64* hpubE  = (u64*)alloc((size_t)2 * 32 * 256 * 8);
  u64* hpubD  = (u64*)alloc((size_t)2 * 32 * 256 * 8);
  u64* qpartD = (u64*)alloc((size_t)2 * 32 * 8 * 256 * 8);
  size_t pub_bytes = o - pub_off;

  hipMemsetAsync(ws + pub_off, 0, pub_bytes, stream);
  hipLaunchKernelGGL(k_prep_x, dim3(1024), dim3(256), 0, stream,
                     src, tgt, enc_emb, enc_Wx, enc_b, dec_emb, dec_Wx, dec_b, Xe, Xd);
  hipLaunchKernelGGL(k_prep_fcw, dim3(2000), dim3(256), 0, stream, fc_W, fcWt);
  hipLaunchKernelGGL(k_encoder8, dim3(256), dim3(256), 0, stream,
                     Xe, enc_Wh, enc_out, h_state, c_state, hpubE);
  hipLaunchKernelGGL(k_keys, dim3(512), dim3(256), 0, stream,
                     enc_out, att_W2, att_b2, keys);
  hipLaunchKernelGGL(k_decoder8, dim3(256), dim3(512), 0, stream,
                     Xd, dec_Wx, dec_Wh, att_W1, att_b1, att_V, att_bV,
                     enc_out, keys, h_state, c_state, Hbf,
                     hpubD, qpartD);
  hipLaunchKernelGGL(k_fc, dim3(8000), dim3(256), 0, stream,
                     Hbf, fcWt, fc_b, out, rs_part);
  hipLaunchKernelGGL(k_rowsum, dim3(16), dim3(256), 0, stream, rs_part, row_inv);
  hipLaunchKernelGGL(k_norm, dim3(2048), dim3(256), 0, stream,
                     (float4*)d_out, row_inv);
}

// Round 4
// 1518.100 us; speedup vs baseline: 5.6136x; 1.1133x over previous
//
#include <hip/hip_runtime.h>
#include <hip/hip_bf16.h>
#include <hip/hip_fp16.h>
#include <cstdint>
#include <cstddef>

#define B_ 32
#define S_ 128
#define T_ 128
#define E_ 128
#define U_ 256
#define V_ 32000
#define G4 1024          // 4*U
#define TV 4096000       // T_*V_

typedef __attribute__((ext_vector_type(8))) short short8_t;   // 8 bf16
typedef __attribute__((ext_vector_type(4))) float f32x4;
typedef unsigned long long u64;

static __device__ __forceinline__ unsigned short f2bf(float x) {
  union { float f; unsigned int u; } v; v.f = x;
  unsigned int r = (v.u + 0x7fffu + ((v.u >> 16) & 1u)) >> 16;
  return (unsigned short)r;
}
static __device__ __forceinline__ unsigned int pack2bf(float a, float b) {
  return (unsigned int)f2bf(a) | ((unsigned int)f2bf(b) << 16);
}
static __device__ __forceinline__ float bf_lo(unsigned int w) { return __uint_as_float(w << 16); }
static __device__ __forceinline__ float bf_hi(unsigned int w) { return __uint_as_float(w & 0xffff0000u); }
static __device__ __forceinline__ float sigmoidf_(float x) {
  return 1.0f / (1.0f + __expf(-x));
}
static __device__ __forceinline__ float tanhf_(float x) {
  float e = __expf(2.0f * x);
  return 1.0f - 2.0f / (e + 1.0f);
}

// ---- e5m2 (truncated fp16) encode ----
static __device__ __forceinline__ unsigned int f2e5(float x) {
  __half h = __float2half(x);
  __half_raw hr = *(__half_raw*)&h;
  unsigned int u = hr.x;
  unsigned int r = (u + 0x7Fu + ((u >> 8) & 1u)) >> 8;   // RNE to 8 bits
  return r & 0xFFu;
}

// ---- packed fp16 helpers (bit-typed half2 in unsigned) ----
static __device__ __forceinline__ unsigned pk2(float a, float b) {
  auto h = __builtin_amdgcn_cvt_pkrtz(a, b);
  return __builtin_bit_cast(unsigned, h);
}
#define SEL01 0x05000400u   // bytes [b1,0,b0,0] -> half2(b0<<8, b1<<8)
#define SEL23 0x07000600u
static __device__ __forceinline__ unsigned e5pair(unsigned w, unsigned sel) {
  return __builtin_amdgcn_perm(w, 0u, sel);
}
static __device__ __forceinline__ float dot2(unsigned a, unsigned b, float c) {
  float d;
  asm("v_dot2_f32_f16 %0, %1, %2, %3" : "=v"(d) : "v"(a), "v"(b), "v"(c));
  return d;
}
static __device__ __forceinline__ unsigned pkadd(unsigned a, unsigned b) {
  unsigned d; asm("v_pk_add_f16 %0, %1, %2" : "=v"(d) : "v"(a), "v"(b)); return d;
}
static __device__ __forceinline__ unsigned pkmul(unsigned a, unsigned b) {
  unsigned d; asm("v_pk_mul_f16 %0, %1, %2" : "=v"(d) : "v"(a), "v"(b)); return d;
}
static __device__ __forceinline__ unsigned pkfma(unsigned a, unsigned b, unsigned c) {
  unsigned d; asm("v_pk_fma_f16 %0, %1, %2, %3" : "=v"(d) : "v"(a), "v"(b), "v"(c)); return d;
}
static __device__ __forceinline__ unsigned pkmax(unsigned a, unsigned b) {
  unsigned d; asm("v_pk_max_f16 %0, %1, %2" : "=v"(d) : "v"(a), "v"(b)); return d;
}
static __device__ __forceinline__ unsigned pkmin(unsigned a, unsigned b) {
  unsigned d; asm("v_pk_min_f16 %0, %1, %2" : "=v"(d) : "v"(a), "v"(b)); return d;
}

// ---- tagged agent-scope publication: payload (f32) + step tag in one u64 ----
static __device__ __forceinline__ void pub64(u64* p, float val, unsigned tag) {
  u64 v = ((u64)tag << 32) | (u64)__float_as_uint(val);
  __hip_atomic_store(p, v, __ATOMIC_RELAXED, __HIP_MEMORY_SCOPE_AGENT);
}
static __device__ __forceinline__ u64 ld64(const u64* p) {
  return __hip_atomic_load(p, __ATOMIC_RELAXED, __HIP_MEMORY_SCOPE_AGENT);
}

// ---------------------------------------------------------------------------
// K1: embedding gather + x@Wx + bias precompute for encoder and decoder.
// ---------------------------------------------------------------------------
__global__ __launch_bounds__(256) void k_prep_x(
    const int* __restrict__ src, const int* __restrict__ tgt,
    const float* __restrict__ enc_emb, const float* __restrict__ enc_Wx,
    const float* __restrict__ enc_b,
    const float* __restrict__ dec_emb, const float* __restrict__ dec_Wx,
    const float* __restrict__ dec_b,
    float* __restrict__ Xe, float* __restrict__ Xd)
{
  __shared__ float emb_l[8][E_];
  int wg = blockIdx.x;
  int tid = threadIdx.x;
  bool is_dec = (wg >= 512);
  int r0 = (is_dec ? (wg - 512) : wg) * 8;
  const float* emb  = is_dec ? dec_emb : enc_emb;
  const float* W    = is_dec ? (dec_Wx + (size_t)U_ * G4) : enc_Wx;
  const float* bias = is_dec ? dec_b : enc_b;
  float* Xout = is_dec ? Xd : Xe;

  for (int i = 0; i < 4; ++i) {
    int lin = i * 256 + tid;
    int rr = lin >> 7, k = lin & 127;
    int r = r0 + rr;               // r = step*32 + b
    int b = r & 31, st = r >> 5;
    int tok;
    if (is_dec) tok = tgt[b * T_ + (st > 0 ? st - 1 : 0)];
    else        tok = src[b * S_ + st];
    emb_l[rr][k] = emb[(size_t)tok * E_ + k];
  }
  __syncthreads();

  float acc[8][4];
  #pragma unroll
  for (int rr = 0; rr < 8; ++rr)
    #pragma unroll
    for (int cc = 0; cc < 4; ++cc) acc[rr][cc] = 0.f;

  for (int k = 0; k < E_; ++k) {
    float w0 = W[(size_t)k * G4 + tid];
    float w1 = W[(size_t)k * G4 + tid + 256];
    float w2 = W[(size_t)k * G4 + tid + 512];
    float w3 = W[(size_t)k * G4 + tid + 768];
    #pragma unroll
    for (int rr = 0; rr < 8; ++rr) {
      float e = emb_l[rr][k];
      acc[rr][0] += e * w0; acc[rr][1] += e * w1;
      acc[rr][2] += e * w2; acc[rr][3] += e * w3;
    }
  }
  #pragma unroll
  for (int rr = 0; rr < 8; ++rr) {
    int r = r0 + rr;
    #pragma unroll
    for (int cc = 0; cc < 4; ++cc) {
      int col = tid + cc * 256;
      Xout[(size_t)r * G4 + col] = acc[rr][cc] + bias[col];
    }
  }
}

// ---------------------------------------------------------------------------
// K2: transpose fc_W [256][32000] f32 -> fcWt [32000][256] bf16
// ---------------------------------------------------------------------------
__global__ __launch_bounds__(256) void k_prep_fcw(
    const float* __restrict__ fcW, unsigned short* __restrict__ fcWt)
{
  __shared__ float tile[64][65];
  int bid = blockIdx.x, tid = threadIdx.x;
  int n0 = (bid % 500) * 64, k0 = (bid / 500) * 64;
  for (int i = 0; i < 16; ++i) {
    int lin = i * 256 + tid;
    int k = lin >> 6, n = lin & 63;
    tile[k][n] = fcW[(size_t)(k0 + k) * V_ + n0 + n];
  }
  __syncthreads();
  for (int i = 0; i < 16; ++i) {
    int lin = i * 256 + tid;
    int n = lin >> 6, k = lin & 63;
    fcWt[(size_t)(n0 + n) * 256 + k0 + k] = f2bf(tile[k][n]);
  }
}

// ---------------------------------------------------------------------------
// K3: encoder LSTM, 8 WGs per batch element (unchanged from R2/R3).
// ---------------------------------------------------------------------------
__global__ __launch_bounds__(256) void k_encoder8(
    const float* __restrict__ Xe, const float* __restrict__ Wh,
    float* __restrict__ enc_out, float* __restrict__ h_state,
    float* __restrict__ c_state, u64* __restrict__ hpubE /*[2][32][256]*/)
{
  __shared__ unsigned int WhL[128][128];   // [k2][cl] packed bf16 pairs, 64KB
  __shared__ float h_l[256];
  __shared__ float zp[2][128];

  int bid = blockIdx.x, tid = threadIdx.x;
  int g = bid & 7, b = bid >> 3;

  {
    int cl = tid & 127, kh = tid >> 7;
    int q = cl >> 5, r = cl & 31;
    int gc = q * 256 + g * 32 + r;
    for (int k2 = kh; k2 < 128; k2 += 2) {
      float w0 = Wh[(size_t)(2 * k2) * G4 + gc];
      float w1 = Wh[(size_t)(2 * k2 + 1) * G4 + gc];
      WhL[k2][cl] = pack2bf(w0, w1);
    }
  }
  float c_reg = 0.f, h_reg = 0.f;
  __syncthreads();

  for (int s = 0; s < S_; ++s) {
    if (s == 0) {
      h_l[tid] = 0.f;
    } else {
      const u64* p = &hpubE[((size_t)(s & 1) * 32 + b) * 256 + tid];
      u64 v = ld64(p);
      while ((unsigned)(v >> 32) < (unsigned)s) { __builtin_amdgcn_s_sleep(1); v = ld64(p); }
      h_l[tid] = __uint_as_float((unsigned)v);
    }
    __syncthreads();
    {
      int half = tid >> 7, cl = tid & 127;
      int k2b = half * 64;
      float acc = 0.f;
      #pragma unroll 8
      for (int k2 = 0; k2 < 64; ++k2) {
        unsigned int w = WhL[k2b + k2][cl];
        acc += h_l[2 * (k2b + k2)]     * bf_lo(w);
        acc += h_l[2 * (k2b + k2) + 1] * bf_hi(w);
      }
      zp[half][cl] = acc;
    }
    __syncthreads();
    if (tid < 32) {
      int r = tid, gc = g * 32 + r;
      const float* xe = Xe + (size_t)(s * B_ + b) * G4;
      float zi = zp[0][r]      + zp[1][r]      + xe[gc];
      float zf = zp[0][32 + r] + zp[1][32 + r] + xe[256 + gc];
      float zg = zp[0][64 + r] + zp[1][64 + r] + xe[512 + gc];
      float zo = zp[0][96 + r] + zp[1][96 + r] + xe[768 + gc];
      float c = sigmoidf_(zf) * c_reg + sigmoidf_(zi) * tanhf_(zg);
      c_reg = c;
      float h = sigmoidf_(zo) * tanhf_(c);
      h_reg = h;
      enc_out[((size_t)(b * S_ + s)) * U_ + gc] = h;
      pub64(&hpubE[((size_t)((s + 1) & 1) * 32 + b) * 256 + gc], h, (unsigned)(s + 1));
    }
  }
  if (tid < 32) {
    h_state[b * U_ + g * 32 + tid] = h_reg;
    c_state[b * U_ + g * 32 + tid] = c_reg;
  }
}

// ---------------------------------------------------------------------------
// K4: keys = enc_out @ att_W2 + b2.
// ---------------------------------------------------------------------------
__global__ __launch_bounds__(256) void k_keys(
    const float* __restrict__ enc_out, const float* __restrict__ W2,
    const float* __restrict__ b2, float* __restrict__ keys)
{
  __shared__ float x_l[8][U_];
  int wg = blockIdx.x, tid = threadIdx.x;
  int r0 = wg * 8;
  for (int i = 0; i < 8; ++i) x_l[i][tid] = enc_out[(size_t)(r0 + i) * U_ + tid];
  __syncthreads();
  float acc[8];
  #pragma unroll
  for (int rr = 0; rr < 8; ++rr) acc[rr] = 0.f;
  for (int k = 0; k < U_; ++k) {
    float w = W2[(size_t)k * U_ + tid];
    #pragma unroll
    for (int rr = 0; rr < 8; ++rr) acc[rr] += x_l[rr][k] * w;
  }
  float bb = b2[tid];
  #pragma unroll
  for (int rr = 0; rr < 8; ++rr)
    keys[(size_t)(r0 + rr) * U_ + tid] = acc[rr] + bb;
}

// ---------------------------------------------------------------------------
// K5 v4: decoder, 8 WGs x 512 threads per b, ONE rendezvous/step.
// Packed-fp16 datapath: v_perm e5m2 decode + v_dot2_f32_f16 MACs + pk-fp16
// tanh poly. Bank-conflict-free quarter-padded q2/aV2; eo transposed [u][s].
// ---------------------------------------------------------------------------
__global__ __launch_bounds__(512) void k_decoder8(
    const float* __restrict__ Xd, const float* __restrict__ dec_Wx,
    const float* __restrict__ Wh,
    const float* __restrict__ W1, const float* __restrict__ b1,
    const float* __restrict__ attV, const float* __restrict__ attbV,
    const float* __restrict__ enc_out, const float* __restrict__ keys,
    const float* __restrict__ h0, const float* __restrict__ c0,
    unsigned short* __restrict__ Hbf,
    u64* __restrict__ hpubD   /*[2][32][256]*/,
    u64* __restrict__ qpartD  /*[2][32][8][256]*/)
{
  __shared__ unsigned int WxU[128 * 65];   // [c][k4] e5m2 bytes (ctx weights)
  __shared__ unsigned int WhU[128 * 65];   // [c][k4] e5m2 bytes (h weights)
  __shared__ unsigned int keyU[128 * 65];  // [s][u4] e5m2 bytes
  __shared__ unsigned int eoT[256 * 33];   // [u][s4] e5m2 bytes (transposed)
  __shared__ unsigned int W1L[16][256];    // fp16 pairs (k2 x u)
  __shared__ unsigned int q2[160];         // half2 q, quarter-padded (4 x 40)
  __shared__ unsigned int aV2[160];        // half2 attV, same layout
  __shared__ unsigned int h2[128];         // half2 h pairs
  __shared__ unsigned int ctx2[128];       // half2 ctx pairs
  __shared__ unsigned int esc2[64];        // half2 esc pairs
  __shared__ float esc_l[128];
  __shared__ float scratch[512];
  __shared__ float hsl[32];
  __shared__ float b1_l[256];
  __shared__ float dinv_l;

  int bid = blockIdx.x, tid = threadIdx.x;
  int b = bid & 31, g = bid >> 5;          // 8 WGs of b on one XCD

  // ---- one-time staging ----
  for (int idx = tid; idx < 128 * 64; idx += 512) {     // Wx/Wh: c x k4
    int c = idx & 127, k4 = idx >> 7;
    int gc = ((c >> 5) << 8) + g * 32 + (c & 31);
    unsigned wx = 0, wh = 0;
    #pragma unroll
    for (int i = 0; i < 4; ++i) {
      int k = k4 * 4 + i;
      wx |= f2e5(dec_Wx[(size_t)k * G4 + gc]) << (8 * i);
      wh |= f2e5(Wh[(size_t)k * G4 + gc]) << (8 * i);
    }
    WxU[c * 65 + k4] = wx;
    WhU[c * 65 + k4] = wh;
  }
  for (int idx = tid; idx < 128 * 64; idx += 512) {     // keys: s x u4
    int s = idx >> 6, u4 = idx & 63;
    float4 kv = *(const float4*)(keys + ((size_t)b * S_ + s) * U_ + u4 * 4);
    keyU[s * 65 + u4] = f2e5(kv.x) | (f2e5(kv.y) << 8) | (f2e5(kv.z) << 16) | (f2e5(kv.w) << 24);
  }
  for (int idx = tid; idx < 256 * 32; idx += 512) {     // eoT: u x s4
    int u = idx & 255, s4 = idx >> 8;
    unsigned w = 0;
    #pragma unroll
    for (int i = 0; i < 4; ++i) {
      int s = s4 * 4 + i;
      w |= f2e5(enc_out[((size_t)b * S_ + s) * U_ + u]) << (8 * i);
    }
    eoT[u * 33 + s4] = w;
  }
  if (tid < 256) {
    #pragma unroll
    for (int k2 = 0; k2 < 16; ++k2)
      W1L[k2][tid] = pk2(W1[(size_t)(g * 32 + 2 * k2) * U_ + tid],
                         W1[(size_t)(g * 32 + 2 * k2 + 1) * U_ + tid]);
    b1_l[tid] = b1[tid];
  }
  if (tid < 128) {   // attV pairs, quarter-padded
    aV2[(tid >> 5) * 40 + (tid & 31)] = pk2(attV[2 * tid], attV[2 * tid + 1]);
  }
  float bV = attbV[0];
  float c_reg = 0.f, h_reg = 0.f;
  if (tid < 32) {
    h_reg = h0[b * U_ + g * 32 + tid];
    c_reg = c0[b * U_ + g * 32 + tid];
    hsl[tid] = h_reg;
  }
  __syncthreads();

  // initial publish: tag 1, parity 0
  if (tid < 256) {
    float qp = 0.f;
    #pragma unroll
    for (int k2 = 0; k2 < 16; ++k2)
      qp = dot2(W1L[k2][tid], pk2(hsl[2 * k2], hsl[2 * k2 + 1]), qp);
    pub64(&qpartD[(((size_t)0 * 32 + b) * 8 + g) * 256 + tid], qp, 1u);
  }
  if (tid < 32)
    pub64(&hpubD[((size_t)0 * 32 + b) * 256 + g * 32 + tid], h_reg, 1u);

  const unsigned NEG1 = pk2(-1.f, -1.f), POS1 = pk2(1.f, 1.f);
  const unsigned C1 = pk2(-0.333333333f, -0.333333333f);
  const unsigned C2 = pk2(0.133333333f, 0.133333333f);
  const unsigned C3 = pk2(-0.053968254f, -0.053968254f);

  for (int t = 0; t < T_; ++t) {
    unsigned tag = (unsigned)(t + 1);
    int par = t & 1;

    // ---- Xd prefetch ----
    float xd0 = 0.f, xd1 = 0.f, xd2 = 0.f, xd3 = 0.f;
    if (tid < 32) {
      const float* xd = Xd + (size_t)(t * B_ + b) * G4;
      int gc = g * 32 + tid;
      xd0 = xd[gc]; xd1 = xd[256 + gc]; xd2 = xd[512 + gc]; xd3 = xd[768 + gc];
    }

    // ---- rendezvous: gather full h + 8 q-partials; build half2 pairs ----
    if (tid < 256) {
      const u64* hp  = &hpubD[((size_t)par * 32 + b) * 256 + tid];
      const u64* qp0 = &qpartD[(((size_t)par * 32 + b) * 8) * 256 + tid];
      u64 vh, vq[8];
      bool ok;
      do {
        vh = ld64(hp);
        #pragma unroll
        for (int gg = 0; gg < 8; ++gg) vq[gg] = ld64(qp0 + (size_t)gg * 256);
        ok = ((unsigned)(vh >> 32) >= tag);
        #pragma unroll
        for (int gg = 0; gg < 8; ++gg) ok &= ((unsigned)(vq[gg] >> 32) >= tag);
        if (!ok) __builtin_amdgcn_s_sleep(1);
      } while (!ok);
      float h = __uint_as_float((unsigned)vh);
      float q = b1_l[tid];
      #pragma unroll
      for (int gg = 0; gg < 8; ++gg) q += __uint_as_float((unsigned)vq[gg]);
      float hp1 = __shfl_xor(h, 1), qp1 = __shfl_xor(q, 1);
      if (!(tid & 1)) {
        h2[tid >> 1] = pk2(h, hp1);
        q2[(tid >> 6) * 40 + ((tid & 63) >> 1)] = pk2(q, qp1);
      }
    }
    __syncthreads();

    // ---- scores: all 128 s, packed fp16 (s = tid>>2, uq = tid&3) ----
    {
      int s = tid >> 2, uq = tid & 3;
      const unsigned* kr = &keyU[s * 65 + uq * 16];
      const unsigned* qq = &q2[uq * 40];
      const unsigned* vv = &aV2[uq * 40];
      float a0 = 0.f, a1 = 0.f;
      #pragma unroll
      for (int j = 0; j < 16; ++j) {
        unsigned w = kr[j];
        #pragma unroll
        for (int p = 0; p < 2; ++p) {
          unsigned x = pkadd(e5pair(w, p ? SEL23 : SEL01), qq[2 * j + p]);
          x = pkmin(pkmax(x, NEG1), POS1);
          unsigned x2 = pkmul(x, x);
          unsigned tt = pkfma(x2, C3, C2);
          tt = pkfma(x2, tt, C1);
          unsigned th = pkfma(pkmul(x, x2), tt, x);
          if (p) a1 = dot2(th, vv[2 * j + 1], a1);
          else   a0 = dot2(th, vv[2 * j], a0);
        }
      }
      float a = a0 + a1;
      a += __shfl_xor(a, 1); a += __shfl_xor(a, 2);
      float ea = __expf(a + bV);
      float ep = __shfl_xor(ea, 4);
      if (uq == 0) {
        esc_l[s] = ea;
        if (!(s & 1)) esc2[s >> 1] = pk2(ea, ep);
      }
    }
    __syncthreads();

    // ---- ctx partials (u = tid&255, s-half = tid>>8) + denominator ----
    {
      int u = tid & 255, sh = tid >> 8;
      const unsigned* ep = &eoT[u * 33 + sh * 16];
      const unsigned* e2 = &esc2[sh * 32];
      float c0a = 0.f, c1a = 0.f;
      #pragma unroll
      for (int j = 0; j < 16; ++j) {
        unsigned w = ep[j];
        c0a = dot2(e5pair(w, SEL01), e2[2 * j], c0a);
        c1a = dot2(e5pair(w, SEL23), e2[2 * j + 1], c1a);
      }
      scratch[sh * 256 + u] = c0a + c1a;
    }
    if (tid < 64) {
      float e = esc_l[tid] + esc_l[tid + 64];
      e += __shfl_xor(e, 1); e += __shfl_xor(e, 2); e += __shfl_xor(e, 4);
      e += __shfl_xor(e, 8); e += __shfl_xor(e, 16); e += __shfl_xor(e, 32);
      if (tid == 0) dinv_l = 1.0f / e;
    }
    __syncthreads();

    // ---- ctx finalize -> half2 pairs ----
    if (tid < 256) {
      float cf = (scratch[tid] + scratch[256 + tid]) * dinv_l;
      float cp = __shfl_xor(cf, 1);
      if (!(tid & 1)) ctx2[tid >> 1] = pk2(cf, cp);
    }
    __syncthreads();

    // ---- z: c = tid&127, k-quarter = tid>>7 ----
    {
      int c = tid & 127, kq = tid >> 7;
      const unsigned* wxp = &WxU[c * 65 + kq * 16];
      const unsigned* whp = &WhU[c * 65 + kq * 16];
      const unsigned* cc2 = &ctx2[kq * 32];
      const unsigned* hh2 = &h2[kq * 32];
      float za = 0.f, zb = 0.f;
      #pragma unroll
      for (int j = 0; j < 16; ++j) {
        unsigned wx = wxp[j], wh = whp[j];
        za = dot2(e5pair(wx, SEL01), cc2[2 * j], za);
        za = dot2(e5pair(wx, SEL23), cc2[2 * j + 1], za);
        zb = dot2(e5pair(wh, SEL01), hh2[2 * j], zb);
        zb = dot2(e5pair(wh, SEL23), hh2[2 * j + 1], zb);
      }
      scratch[kq * 128 + c] = za + zb;
    }
    __syncthreads();

    // ---- pointwise LSTM update on own 32 units ----
    if (tid < 32) {
      int r = tid, gc = g * 32 + r;
      float zi = scratch[r]      + scratch[128 + r]      + scratch[256 + r]      + scratch[384 + r]      + xd0;
      float zf = scratch[32 + r] + scratch[128 + 32 + r] + scratch[256 + 32 + r] + scratch[384 + 32 + r] + xd1;
      float zg = scratch[64 + r] + scratch[128 + 64 + r] + scratch[256 + 64 + r] + scratch[384 + 64 + r] + xd2;
      float zo = scratch[96 + r] + scratch[128 + 96 + r] + scratch[256 + 96 + r] + scratch[384 + 96 + r] + xd3;
      float c = sigmoidf_(zf) * c_reg + sigmoidf_(zi) * tanhf_(zg);
      c_reg = c;
      float h = sigmoidf_(zo) * tanhf_(c);
      h_reg = h;
      hsl[r] = h;
      Hbf[(size_t)(t * B_ + b) * U_ + gc] = f2bf(h);
    }
    __syncthreads();

    // ---- publish h' + qpart' for step t+1 ----
    if (t < T_ - 1) {
      int par1 = (t + 1) & 1;
      unsigned tag2 = (unsigned)(t + 2);
      if (tid < 256) {
        float qp = 0.f;
        #pragma unroll
        for (int k2 = 0; k2 < 16; ++k2)
          qp = dot2(W1L[k2][tid], pk2(hsl[2 * k2], hsl[2 * k2 + 1]), qp);
        pub64(&qpartD[(((size_t)par1 * 32 + b) * 8 + g) * 256 + tid], qp, tag2);
      }
      if (tid < 32)
        pub64(&hpubD[((size_t)par1 * 32 + b) * 256 + g * 32 + tid], h_reg, tag2);
    }
  }
}

// ---------------------------------------------------------------------------
// K6: fc GEMM (MFMA bf16) + exp epilogue + row-sum partials.
// bid swizzle: 32 consecutive WGs share one B tile (L2-resident Hbf + B).
// ---------------------------------------------------------------------------
__global__ __launch_bounds__(256) void k_fc(
    const unsigned short* __restrict__ Hbf, const unsigned short* __restrict__ fcWt,
    const float* __restrict__ fcb, float* __restrict__ out,
    float* __restrict__ rs_part)
{
  __shared__ uint4 Al[128 * 8];
  __shared__ uint4 Bl[128 * 8];
  __shared__ float rsum_l[128][2];

  int bid = blockIdx.x, tid = threadIdx.x;
  int nt = bid >> 5, mt = bid & 31;
  int m0 = mt * 128, n0 = nt * 128;
  int lane = tid & 63, wave = tid >> 6;
  int wm = (wave >> 1) * 64, wn = (wave & 1) * 64;
  int g = lane >> 4, r15 = lane & 15;

  f32x4 acc[4][4];
  f32x4 zero = {0.f, 0.f, 0.f, 0.f};
  #pragma unroll
  for (int mi = 0; mi < 4; ++mi)
    #pragma unroll
    for (int ni = 0; ni < 4; ++ni) acc[mi][ni] = zero;

  const unsigned short* Ag = Hbf  + (size_t)m0 * 256;
  const unsigned short* Bg = fcWt + (size_t)n0 * 256;

  for (int kt = 0; kt < 4; ++kt) {
    int kk = kt * 64;
    #pragma unroll
    for (int blk = 0; blk < 4; ++blk) {
      int lin = blk * 256 + tid;
      int row = lin >> 3, kq = lin & 7;
      Al[row * 8 + (kq ^ (row & 7))] = *(const uint4*)(Ag + (size_t)row * 256 + kk + kq * 8);
      Bl[row * 8 + (kq ^ (row & 7))] = *(const uint4*)(Bg + (size_t)row * 256 + kk + kq * 8);
    }
    __syncthreads();
    #pragma unroll
    for (int kk2 = 0; kk2 < 2; ++kk2) {
      short8_t a[4], bfr[4];
      #pragma unroll
      for (int mi = 0; mi < 4; ++mi) {
        int row = wm + mi * 16 + r15;
        a[mi] = *(const short8_t*)&Al[row * 8 + ((kk2 * 4 + g) ^ (row & 7))];
      }
      #pragma unroll
      for (int ni = 0; ni < 4; ++ni) {
        int row = wn + ni * 16 + r15;
        bfr[ni] = *(const short8_t*)&Bl[row * 8 + ((kk2 * 4 + g) ^ (row & 7))];
      }
      #pragma unroll
      for (int mi = 0; mi < 4; ++mi)
        #pragma unroll
        for (int ni = 0; ni < 4; ++ni)
          acc[mi][ni] = __builtin_amdgcn_mfma_f32_16x16x32_bf16(a[mi], bfr[ni], acc[mi][ni], 0, 0, 0);
    }
    __syncthreads();
  }

  float fcb_l[4];
  #pragma unroll
  for (int ni = 0; ni < 4; ++ni) fcb_l[ni] = fcb[n0 + wn + ni * 16 + r15];

  #pragma unroll
  for (int mi = 0; mi < 4; ++mi) {
    #pragma unroll
    for (int jj = 0; jj < 4; ++jj) {
      int rloc = wm + mi * 16 + g * 4 + jj;
      int grow = m0 + rloc;                     // = t*32 + b
      int bb = grow & 31, tt = grow >> 5;
      size_t obase = (size_t)bb * TV + (size_t)tt * V_;
      float s = 0.f;
      #pragma unroll
      for (int ni = 0; ni < 4; ++ni) {
        float v = __expf(acc[mi][ni][jj] + fcb_l[ni]);
        out[obase + n0 + wn + ni * 16 + r15] = v;
        s += v;
      }
      s += __shfl_xor(s, 1); s += __shfl_xor(s, 2);
      s += __shfl_xor(s, 4); s += __shfl_xor(s, 8);
      if (r15 == 0) rsum_l[rloc][wave & 1] = s;
    }
  }
  __syncthreads();
  if (tid < 128)
    rs_part[(size_t)nt * 4096 + m0 + tid] = rsum_l[tid][0] + rsum_l[tid][1];
}

// ---------------------------------------------------------------------------
// K7: reduce partial row sums -> 1/sum per GEMM row
// ---------------------------------------------------------------------------
__global__ __launch_bounds__(256) void k_rowsum(
    const float* __restrict__ rs_part, float* __restrict__ row_inv)
{
  int gidx = blockIdx.x * 256 + threadIdx.x;
  float s = 0.f;
  for (int nt = 0; nt < 250; ++nt) s += rs_part[(size_t)nt * 4096 + gidx];
  row_inv[gidx] = 1.0f / s;
}

// ---------------------------------------------------------------------------
// K8: normalize probs in place
// ---------------------------------------------------------------------------
__global__ __launch_bounds__(256) void k_norm(
    float4* __restrict__ out4, const float* __restrict__ row_inv)
{
  const long total = 32768000;
  long stride = (long)gridDim.x * 256;
  for (long i = (long)blockIdx.x * 256 + threadIdx.x; i < total; i += stride) {
    long flat = i * 4;
    int bb = (int)(flat / TV);
    int rem = (int)(flat % TV);
    int tt = rem / V_;
    float sc = row_inv[tt * 32 + bb];
    float4 v = out4[i];
    v.x *= sc; v.y *= sc; v.z *= sc; v.w *= sc;
    out4[i] = v;
  }
}

// ---------------------------------------------------------------------------
extern "C" void kernel_launch(void* const* d_in, const int* in_sizes, int n_in,
                              void* d_out, int out_size, void* d_ws, size_t ws_size,
                              hipStream_t stream) {
  (void)in_sizes; (void)n_in; (void)out_size; (void)ws_size;
  const int*   src     = (const int*)d_in[0];
  const int*   tgt     = (const int*)d_in[1];
  const float* enc_emb = (const float*)d_in[2];
  const float* enc_Wx  = (const float*)d_in[3];
  const float* enc_Wh  = (const float*)d_in[4];
  const float* enc_b   = (const float*)d_in[5];
  const float* dec_emb = (const float*)d_in[6];
  const float* dec_Wx  = (const float*)d_in[7];
  const float* dec_Wh  = (const float*)d_in[8];
  const float* dec_b   = (const float*)d_in[9];
  const float* att_W1  = (const float*)d_in[10];
  const float* att_b1  = (const float*)d_in[11];
  const float* att_W2  = (const float*)d_in[12];
  const float* att_b2  = (const float*)d_in[13];
  const float* att_V   = (const float*)d_in[14];
  const float* att_bV  = (const float*)d_in[15];
  const float* fc_W    = (const float*)d_in[16];
  const float* fc_b    = (const float*)d_in[17];
  float* out = (float*)d_out;

  char* ws = (char*)d_ws;
  size_t o = 0;
  auto alloc = [&](size_t bytes) {
    char* p = ws + o;
    o = (o + bytes + 255) & ~(size_t)255;
    return p;
  };
  float*          Xe      = (float*)alloc((size_t)S_ * B_ * G4 * 4);
  float*          Xd      = (float*)alloc((size_t)T_ * B_ * G4 * 4);
  float*          enc_out = (float*)alloc((size_t)B_ * S_ * U_ * 4);
  float*          keys    = (float*)alloc((size_t)B_ * S_ * U_ * 4);
  unsigned short* Hbf     = (unsigned short*)alloc((size_t)T_ * B_ * U_ * 2);
  unsigned short* fcWt    = (unsigned short*)alloc((size_t)V_ * U_ * 2);
  float*          h_state = (float*)alloc((size_t)B_ * U_ * 4);
  float*          c_state = (float*)alloc((size_t)B_ * U_ * 4);
  float*          rs_part = (float*)alloc((size_t)250 * 4096 * 4);
  float*          row_inv = (float*)alloc((size_t)4096 * 4);
  // tagged publication buffers (zeroed each launch for graph replay)
  size_t pub_off = o;
  u64* hpubE  = (u64*)alloc((size_t)2 * 32 * 256 * 8);
  u64* hpubD  = (u64*)alloc((size_t)2 * 32 * 256 * 8);
  u64* qpartD = (u64*)alloc((size_t)2 * 32 * 8 * 256 * 8);
  size_t pub_bytes = o - pub_off;

  hipMemsetAsync(ws + pub_off, 0, pub_bytes, stream);
  hipLaunchKernelGGL(k_prep_x, dim3(1024), dim3(256), 0, stream,
                     src, tgt, enc_emb, enc_Wx, enc_b, dec_emb, dec_Wx, dec_b, Xe, Xd);
  hipLaunchKernelGGL(k_prep_fcw, dim3(2000), dim3(256), 0, stream, fc_W, fcWt);
  hipLaunchKernelGGL(k_encoder8, dim3(256), dim3(256), 0, stream,
                     Xe, enc_Wh, enc_out, h_state, c_state, hpubE);
  hipLaunchKernelGGL(k_keys, dim3(512), dim3(256), 0, stream,
                     enc_out, att_W2, att_b2, keys);
  hipLaunchKernelGGL(k_decoder8, dim3(256), dim3(512), 0, stream,
                     Xd, dec_Wx, dec_Wh, att_W1, att_b1, att_V, att_bV,
                     enc_out, keys, h_state, c_state, Hbf,
                     hpubD, qpartD);
  hipLaunchKernelGGL(k_fc, dim3(8000), dim3(256), 0, stream,
                     Hbf, fcWt, fc_b, out, rs_part);
  hipLaunchKernelGGL(k_rowsum, dim3(16), dim3(256), 0, stream, rs_part, row_inv);
  hipLaunchKernelGGL(k_norm, dim3(2048), dim3(256), 0, stream,
                     (float4*)d_out, row_inv);
}

// Round 5
// 1510.863 us; speedup vs baseline: 5.6405x; 1.0048x over previous
//
#include <hip/hip_runtime.h>
#include <hip/hip_bf16.h>
#include <hip/hip_fp16.h>
#include <cstdint>
#include <cstddef>

#define B_ 32
#define S_ 128
#define T_ 128
#define E_ 128
#define U_ 256
#define V_ 32000
#define G4 1024          // 4*U
#define TV 4096000       // T_*V_

typedef __attribute__((ext_vector_type(8))) short short8_t;   // 8 bf16
typedef __attribute__((ext_vector_type(4))) float f32x4;
typedef unsigned long long u64;

static __device__ __forceinline__ unsigned short f2bf(float x) {
  union { float f; unsigned int u; } v; v.f = x;
  unsigned int r = (v.u + 0x7fffu + ((v.u >> 16) & 1u)) >> 16;
  return (unsigned short)r;
}
static __device__ __forceinline__ unsigned int pack2bf(float a, float b) {
  return (unsigned int)f2bf(a) | ((unsigned int)f2bf(b) << 16);
}
static __device__ __forceinline__ float bf_lo(unsigned int w) { return __uint_as_float(w << 16); }
static __device__ __forceinline__ float bf_hi(unsigned int w) { return __uint_as_float(w & 0xffff0000u); }
static __device__ __forceinline__ float sigmoidf_(float x) {
  return 1.0f / (1.0f + __expf(-x));
}
static __device__ __forceinline__ float tanhf_(float x) {
  float e = __expf(2.0f * x);
  return 1.0f - 2.0f / (e + 1.0f);
}

// ---- e5m2 (truncated fp16) encode ----
static __device__ __forceinline__ unsigned int f2e5(float x) {
  __half h = __float2half(x);
  __half_raw hr = *(__half_raw*)&h;
  unsigned int u = hr.x;
  unsigned int r = (u + 0x7Fu + ((u >> 8) & 1u)) >> 8;   // RNE to 8 bits
  return r & 0xFFu;
}

// ---- packed fp16 helpers (bit-typed half2 in unsigned) ----
static __device__ __forceinline__ unsigned pk2(float a, float b) {
  auto h = __builtin_amdgcn_cvt_pkrtz(a, b);
  return __builtin_bit_cast(unsigned, h);
}
#define SEL01 0x05000400u   // bytes -> half2(b0<<8, b1<<8)
#define SEL23 0x07000600u
static __device__ __forceinline__ unsigned e5pair(unsigned w, unsigned sel) {
  return __builtin_amdgcn_perm(w, 0u, sel);
}
static __device__ __forceinline__ float dot2(unsigned a, unsigned b, float c) {
  float d;
  asm("v_dot2_f32_f16 %0, %1, %2, %3" : "=v"(d) : "v"(a), "v"(b), "v"(c));
  return d;
}
static __device__ __forceinline__ unsigned pkadd(unsigned a, unsigned b) {
  unsigned d; asm("v_pk_add_f16 %0, %1, %2" : "=v"(d) : "v"(a), "v"(b)); return d;
}
static __device__ __forceinline__ unsigned pkmul(unsigned a, unsigned b) {
  unsigned d; asm("v_pk_mul_f16 %0, %1, %2" : "=v"(d) : "v"(a), "v"(b)); return d;
}
static __device__ __forceinline__ unsigned pkfma(unsigned a, unsigned b, unsigned c) {
  unsigned d; asm("v_pk_fma_f16 %0, %1, %2, %3" : "=v"(d) : "v"(a), "v"(b), "v"(c)); return d;
}
static __device__ __forceinline__ unsigned pkmax(unsigned a, unsigned b) {
  unsigned d; asm("v_pk_max_f16 %0, %1, %2" : "=v"(d) : "v"(a), "v"(b)); return d;
}
static __device__ __forceinline__ unsigned pkmin(unsigned a, unsigned b) {
  unsigned d; asm("v_pk_min_f16 %0, %1, %2" : "=v"(d) : "v"(a), "v"(b)); return d;
}

// ---- tagged agent-scope publication ----
static __device__ __forceinline__ void pub64u(u64* p, unsigned val, unsigned tag) {
  u64 v = ((u64)tag << 32) | (u64)val;
  __hip_atomic_store(p, v, __ATOMIC_RELAXED, __HIP_MEMORY_SCOPE_AGENT);
}
static __device__ __forceinline__ void pub64(u64* p, float val, unsigned tag) {
  pub64u(p, __float_as_uint(val), tag);
}
static __device__ __forceinline__ u64 ld64(const u64* p) {
  return __hip_atomic_load(p, __ATOMIC_RELAXED, __HIP_MEMORY_SCOPE_AGENT);
}

// ---------------------------------------------------------------------------
// K1: embedding gather + x@Wx + bias precompute for encoder and decoder.
// ---------------------------------------------------------------------------
__global__ __launch_bounds__(256) void k_prep_x(
    const int* __restrict__ src, const int* __restrict__ tgt,
    const float* __restrict__ enc_emb, const float* __restrict__ enc_Wx,
    const float* __restrict__ enc_b,
    const float* __restrict__ dec_emb, const float* __restrict__ dec_Wx,
    const float* __restrict__ dec_b,
    float* __restrict__ Xe, float* __restrict__ Xd)
{
  __shared__ float emb_l[8][E_];
  int wg = blockIdx.x;
  int tid = threadIdx.x;
  bool is_dec = (wg >= 512);
  int r0 = (is_dec ? (wg - 512) : wg) * 8;
  const float* emb  = is_dec ? dec_emb : enc_emb;
  const float* W    = is_dec ? (dec_Wx + (size_t)U_ * G4) : enc_Wx;
  const float* bias = is_dec ? dec_b : enc_b;
  float* Xout = is_dec ? Xd : Xe;

  for (int i = 0; i < 4; ++i) {
    int lin = i * 256 + tid;
    int rr = lin >> 7, k = lin & 127;
    int r = r0 + rr;               // r = step*32 + b
    int b = r & 31, st = r >> 5;
    int tok;
    if (is_dec) tok = tgt[b * T_ + (st > 0 ? st - 1 : 0)];
    else        tok = src[b * S_ + st];
    emb_l[rr][k] = emb[(size_t)tok * E_ + k];
  }
  __syncthreads();

  float acc[8][4];
  #pragma unroll
  for (int rr = 0; rr < 8; ++rr)
    #pragma unroll
    for (int cc = 0; cc < 4; ++cc) acc[rr][cc] = 0.f;

  for (int k = 0; k < E_; ++k) {
    float w0 = W[(size_t)k * G4 + tid];
    float w1 = W[(size_t)k * G4 + tid + 256];
    float w2 = W[(size_t)k * G4 + tid + 512];
    float w3 = W[(size_t)k * G4 + tid + 768];
    #pragma unroll
    for (int rr = 0; rr < 8; ++rr) {
      float e = emb_l[rr][k];
      acc[rr][0] += e * w0; acc[rr][1] += e * w1;
      acc[rr][2] += e * w2; acc[rr][3] += e * w3;
    }
  }
  #pragma unroll
  for (int rr = 0; rr < 8; ++rr) {
    int r = r0 + rr;
    #pragma unroll
    for (int cc = 0; cc < 4; ++cc) {
      int col = tid + cc * 256;
      Xout[(size_t)r * G4 + col] = acc[rr][cc] + bias[col];
    }
  }
}

// ---------------------------------------------------------------------------
// K2: transpose fc_W [256][32000] f32 -> fcWt [32000][256] bf16
// ---------------------------------------------------------------------------
__global__ __launch_bounds__(256) void k_prep_fcw(
    const float* __restrict__ fcW, unsigned short* __restrict__ fcWt)
{
  __shared__ float tile[64][65];
  int bid = blockIdx.x, tid = threadIdx.x;
  int n0 = (bid % 500) * 64, k0 = (bid / 500) * 64;
  for (int i = 0; i < 16; ++i) {
    int lin = i * 256 + tid;
    int k = lin >> 6, n = lin & 63;
    tile[k][n] = fcW[(size_t)(k0 + k) * V_ + n0 + n];
  }
  __syncthreads();
  for (int i = 0; i < 16; ++i) {
    int lin = i * 256 + tid;
    int n = lin >> 6, k = lin & 63;
    fcWt[(size_t)(n0 + n) * 256 + k0 + k] = f2bf(tile[k][n]);
  }
}

// ---------------------------------------------------------------------------
// K3: encoder LSTM, 8 WGs per batch element; 4-accumulator ILP in z GEMV.
// ---------------------------------------------------------------------------
__global__ __launch_bounds__(256) void k_encoder8(
    const float* __restrict__ Xe, const float* __restrict__ Wh,
    float* __restrict__ enc_out, float* __restrict__ h_state,
    float* __restrict__ c_state, u64* __restrict__ hpubE /*[2][32][256]*/)
{
  __shared__ unsigned int WhL[128][128];   // [k2][cl] packed bf16 pairs, 64KB
  __shared__ float h_l[256];
  __shared__ float zp[2][128];

  int bid = blockIdx.x, tid = threadIdx.x;
  int g = bid & 7, b = bid >> 3;

  {
    int cl = tid & 127, kh = tid >> 7;
    int q = cl >> 5, r = cl & 31;
    int gc = q * 256 + g * 32 + r;
    for (int k2 = kh; k2 < 128; k2 += 2) {
      float w0 = Wh[(size_t)(2 * k2) * G4 + gc];
      float w1 = Wh[(size_t)(2 * k2 + 1) * G4 + gc];
      WhL[k2][cl] = pack2bf(w0, w1);
    }
  }
  float c_reg = 0.f, h_reg = 0.f;
  __syncthreads();

  for (int s = 0; s < S_; ++s) {
    if (s == 0) {
      h_l[tid] = 0.f;
    } else {
      const u64* p = &hpubE[((size_t)(s & 1) * 32 + b) * 256 + tid];
      u64 v = ld64(p);
      while ((unsigned)(v >> 32) < (unsigned)s) { __builtin_amdgcn_s_sleep(1); v = ld64(p); }
      h_l[tid] = __uint_as_float((unsigned)v);
    }
    __syncthreads();
    {
      int half = tid >> 7, cl = tid & 127;
      int k2b = half * 64;
      float a0 = 0.f, a1 = 0.f, a2 = 0.f, a3 = 0.f;
      #pragma unroll 4
      for (int k2 = 0; k2 < 64; k2 += 4) {
        unsigned w0 = WhL[k2b + k2][cl];
        unsigned w1 = WhL[k2b + k2 + 1][cl];
        unsigned w2 = WhL[k2b + k2 + 2][cl];
        unsigned w3 = WhL[k2b + k2 + 3][cl];
        a0 += h_l[2*(k2b+k2)]   * bf_lo(w0) + h_l[2*(k2b+k2)+1] * bf_hi(w0);
        a1 += h_l[2*(k2b+k2)+2] * bf_lo(w1) + h_l[2*(k2b+k2)+3] * bf_hi(w1);
        a2 += h_l[2*(k2b+k2)+4] * bf_lo(w2) + h_l[2*(k2b+k2)+5] * bf_hi(w2);
        a3 += h_l[2*(k2b+k2)+6] * bf_lo(w3) + h_l[2*(k2b+k2)+7] * bf_hi(w3);
      }
      zp[half][cl] = (a0 + a1) + (a2 + a3);
    }
    __syncthreads();
    if (tid < 32) {
      int r = tid, gc = g * 32 + r;
      const float* xe = Xe + (size_t)(s * B_ + b) * G4;
      float zi = zp[0][r]      + zp[1][r]      + xe[gc];
      float zf = zp[0][32 + r] + zp[1][32 + r] + xe[256 + gc];
      float zg = zp[0][64 + r] + zp[1][64 + r] + xe[512 + gc];
      float zo = zp[0][96 + r] + zp[1][96 + r] + xe[768 + gc];
      float c = sigmoidf_(zf) * c_reg + sigmoidf_(zi) * tanhf_(zg);
      c_reg = c;
      float h = sigmoidf_(zo) * tanhf_(c);
      h_reg = h;
      enc_out[((size_t)(b * S_ + s)) * U_ + gc] = h;
      pub64(&hpubE[((size_t)((s + 1) & 1) * 32 + b) * 256 + gc], h, (unsigned)(s + 1));
    }
  }
  if (tid < 32) {
    h_state[b * U_ + g * 32 + tid] = h_reg;
    c_state[b * U_ + g * 32 + tid] = c_reg;
  }
}

// ---------------------------------------------------------------------------
// K4: keys = enc_out @ att_W2 + b2.
// ---------------------------------------------------------------------------
__global__ __launch_bounds__(256) void k_keys(
    const float* __restrict__ enc_out, const float* __restrict__ W2,
    const float* __restrict__ b2, float* __restrict__ keys)
{
  __shared__ float x_l[8][U_];
  int wg = blockIdx.x, tid = threadIdx.x;
  int r0 = wg * 8;
  for (int i = 0; i < 8; ++i) x_l[i][tid] = enc_out[(size_t)(r0 + i) * U_ + tid];
  __syncthreads();
  float acc[8];
  #pragma unroll
  for (int rr = 0; rr < 8; ++rr) acc[rr] = 0.f;
  for (int k = 0; k < U_; ++k) {
    float w = W2[(size_t)k * U_ + tid];
    #pragma unroll
    for (int rr = 0; rr < 8; ++rr) acc[rr] += x_l[rr][k] * w;
  }
  float bb = b2[tid];
  #pragma unroll
  for (int rr = 0; rr < 8; ++rr)
    keys[(size_t)(r0 + rr) * U_ + tid] = acc[rr] + bb;
}

// ---------------------------------------------------------------------------
// K5 v5: decoder, 8 WGs x 512 threads per b, ONE rendezvous/step.
// fp16-packed publications (tag||half2). Phases:
//  P1 poll+build q2/h2 | P2 scores + z_h + wave-denoms | P3 ctx partials
//  P4 ctx finalize | P5 z_ctx (+=) | P6 pointwise + h-pub | P7 qpart-pub
// ---------------------------------------------------------------------------
__global__ __launch_bounds__(512) void k_decoder8(
    const float* __restrict__ Xd, const float* __restrict__ dec_Wx,
    const float* __restrict__ Wh,
    const float* __restrict__ W1, const float* __restrict__ b1,
    const float* __restrict__ attV, const float* __restrict__ attbV,
    const float* __restrict__ enc_out, const float* __restrict__ keys,
    const float* __restrict__ h0, const float* __restrict__ c0,
    unsigned short* __restrict__ Hbf,
    u64* __restrict__ hpub2 /*[2][32][128]*/,
    u64* __restrict__ qp2   /*[2][32][128][8]*/)
{
  __shared__ unsigned int WxU[128 * 65];   // [c][k4] e5m2 bytes (ctx weights)
  __shared__ unsigned int WhU[128 * 65];   // [c][k4] e5m2 bytes (h weights)
  __shared__ unsigned int keyU[128 * 65];  // [s][u4] e5m2 bytes
  __shared__ unsigned int eoT[256 * 33];   // [u][s4] e5m2 bytes (transposed)
  __shared__ unsigned int W1L[16][256];    // fp16 pairs (k2 x u)
  __shared__ unsigned int q2[160];         // half2 q, quarter-padded (4 x 40)
  __shared__ unsigned int aV2[160];        // half2 attV, same layout
  __shared__ unsigned int b1p[128];        // half2 b1 pairs
  __shared__ unsigned int h2[128];         // half2 h pairs
  __shared__ unsigned int ctx2[128];       // half2 ctx pairs
  __shared__ unsigned int esc2[64];        // half2 esc pairs
  __shared__ float escw[8];                // per-wave exp-sum partials
  __shared__ float scr_c[512];             // ctx partials [2][256]
  __shared__ float scr_z[512];             // z partials [4][128]
  __shared__ float hsl[32];

  int bid = blockIdx.x, tid = threadIdx.x;
  int b = bid & 31, g = bid >> 5;          // 8 WGs of b on one XCD
  int lane = tid & 63, wid = tid >> 6;

  // ---- one-time staging ----
  for (int idx = tid; idx < 128 * 64; idx += 512) {     // Wx/Wh: c x k4
    int c = idx & 127, k4 = idx >> 7;
    int gc = ((c >> 5) << 8) + g * 32 + (c & 31);
    unsigned wx = 0, wh = 0;
    #pragma unroll
    for (int i = 0; i < 4; ++i) {
      int k = k4 * 4 + i;
      wx |= f2e5(dec_Wx[(size_t)k * G4 + gc]) << (8 * i);
      wh |= f2e5(Wh[(size_t)k * G4 + gc]) << (8 * i);
    }
    WxU[c * 65 + k4] = wx;
    WhU[c * 65 + k4] = wh;
  }
  for (int idx = tid; idx < 128 * 64; idx += 512) {     // keys: s x u4
    int s = idx >> 6, u4 = idx & 63;
    float4 kv = *(const float4*)(keys + ((size_t)b * S_ + s) * U_ + u4 * 4);
    keyU[s * 65 + u4] = f2e5(kv.x) | (f2e5(kv.y) << 8) | (f2e5(kv.z) << 16) | (f2e5(kv.w) << 24);
  }
  for (int idx = tid; idx < 256 * 32; idx += 512) {     // eoT: u x s4
    int u = idx & 255, s4 = idx >> 8;
    unsigned w = 0;
    #pragma unroll
    for (int i = 0; i < 4; ++i) {
      int s = s4 * 4 + i;
      w |= f2e5(enc_out[((size_t)b * S_ + s) * U_ + u]) << (8 * i);
    }
    eoT[u * 33 + s4] = w;
  }
  if (tid < 256) {
    #pragma unroll
    for (int k2 = 0; k2 < 16; ++k2)
      W1L[k2][tid] = pk2(W1[(size_t)(g * 32 + 2 * k2) * U_ + tid],
                         W1[(size_t)(g * 32 + 2 * k2 + 1) * U_ + tid]);
  }
  if (tid < 128) {
    aV2[(tid >> 5) * 40 + (tid & 31)] = pk2(attV[2 * tid], attV[2 * tid + 1]);
    b1p[tid] = pk2(b1[2 * tid], b1[2 * tid + 1]);
  }
  float bV = attbV[0];
  float c_reg = 0.f, h_reg = 0.f;
  if (tid < 32) {
    h_reg = h0[b * U_ + g * 32 + tid];
    c_reg = c0[b * U_ + g * 32 + tid];
    hsl[tid] = h_reg;
  }
  __syncthreads();

  // ---- initial publish: tag 1, parity 0 ----
  if (tid < 256) {
    float qp0 = 0.f, qp1 = 0.f;
    #pragma unroll
    for (int k2 = 0; k2 < 16; k2 += 2) {
      qp0 = dot2(W1L[k2][tid],     pk2(hsl[2*k2],   hsl[2*k2+1]), qp0);
      qp1 = dot2(W1L[k2+1][tid],   pk2(hsl[2*k2+2], hsl[2*k2+3]), qp1);
    }
    float qp = qp0 + qp1;
    float qpx = __shfl_xor(qp, 1);
    if (!(tid & 1))
      pub64u(&qp2[(((size_t)0 * 32 + b) * 128 + (tid >> 1)) * 8 + g], pk2(qp, qpx), 1u);
  }
  if (tid < 32) {
    float hx = __shfl_xor(h_reg, 1);
    if (!(tid & 1))
      pub64u(&hpub2[((size_t)0 * 32 + b) * 128 + g * 16 + (tid >> 1)], pk2(h_reg, hx), 1u);
  }

  const unsigned NEG1 = pk2(-1.f, -1.f), POS1 = pk2(1.f, 1.f);
  const unsigned C1 = pk2(-0.333333333f, -0.333333333f);
  const unsigned C2 = pk2(0.133333333f, 0.133333333f);
  const unsigned C3 = pk2(-0.053968254f, -0.053968254f);

  for (int t = 0; t < T_; ++t) {
    unsigned tag = (unsigned)(t + 1);
    int par = t & 1;

    // ---- Xd prefetch ----
    float xd0 = 0.f, xd1 = 0.f, xd2 = 0.f, xd3 = 0.f;
    if (tid < 32) {
      const float* xd = Xd + (size_t)(t * B_ + b) * G4;
      int gc = g * 32 + tid;
      xd0 = xd[gc]; xd1 = xd[256 + gc]; xd2 = xd[512 + gc]; xd3 = xd[768 + gc];
    }

    // ---- P1: poll (1 h-word + 8 contiguous q-words) + build h2/q2 ----
    if (tid < 128) {
      const u64* hp = &hpub2[((size_t)par * 32 + b) * 128 + tid];
      const u64* qp = &qp2[(((size_t)par * 32 + b) * 128 + tid) * 8];
      u64 vh, vq[8];
      bool ok;
      do {
        vh = ld64(hp);
        #pragma unroll
        for (int gg = 0; gg < 8; ++gg) vq[gg] = ld64(qp + gg);
        ok = ((unsigned)(vh >> 32) >= tag);
        #pragma unroll
        for (int gg = 0; gg < 8; ++gg) ok &= ((unsigned)(vq[gg] >> 32) >= tag);
        if (!ok) __builtin_amdgcn_s_sleep(1);
      } while (!ok);
      h2[tid] = (unsigned)vh;
      unsigned s0 = pkadd((unsigned)vq[0], (unsigned)vq[1]);
      unsigned s1 = pkadd((unsigned)vq[2], (unsigned)vq[3]);
      unsigned s2 = pkadd((unsigned)vq[4], (unsigned)vq[5]);
      unsigned s3 = pkadd((unsigned)vq[6], (unsigned)vq[7]);
      unsigned qs = pkadd(pkadd(s0, s1), pkadd(s2, s3));
      q2[(tid >> 5) * 40 + (tid & 31)] = pkadd(qs, b1p[tid]);
    }
    __syncthreads();

    // ---- P2: scores (all 128 s) + z_h partial + wave denom partials ----
    {
      int s = tid >> 2, uq = tid & 3;
      const unsigned* kr = &keyU[s * 65 + uq * 16];
      const unsigned* qq = &q2[uq * 40];
      const unsigned* vv = &aV2[uq * 40];
      float a0 = 0.f, a1 = 0.f, a2 = 0.f, a3 = 0.f;
      #pragma unroll
      for (int j = 0; j < 16; j += 2) {
        unsigned w0 = kr[j], w1 = kr[j + 1];
        unsigned x0 = pkadd(e5pair(w0, SEL01), qq[2 * j]);
        unsigned x1 = pkadd(e5pair(w0, SEL23), qq[2 * j + 1]);
        unsigned x2 = pkadd(e5pair(w1, SEL01), qq[2 * j + 2]);
        unsigned x3 = pkadd(e5pair(w1, SEL23), qq[2 * j + 3]);
        x0 = pkmin(pkmax(x0, NEG1), POS1);
        x1 = pkmin(pkmax(x1, NEG1), POS1);
        x2 = pkmin(pkmax(x2, NEG1), POS1);
        x3 = pkmin(pkmax(x3, NEG1), POS1);
        unsigned s0_ = pkmul(x0, x0), s1_ = pkmul(x1, x1);
        unsigned s2_ = pkmul(x2, x2), s3_ = pkmul(x3, x3);
        unsigned t0 = pkfma(s0_, C3, C2), t1 = pkfma(s1_, C3, C2);
        unsigned t2 = pkfma(s2_, C3, C2), t3 = pkfma(s3_, C3, C2);
        t0 = pkfma(s0_, t0, C1); t1 = pkfma(s1_, t1, C1);
        t2 = pkfma(s2_, t2, C1); t3 = pkfma(s3_, t3, C1);
        unsigned th0 = pkfma(pkmul(x0, s0_), t0, x0);
        unsigned th1 = pkfma(pkmul(x1, s1_), t1, x1);
        unsigned th2 = pkfma(pkmul(x2, s2_), t2, x2);
        unsigned th3 = pkfma(pkmul(x3, s3_), t3, x3);
        a0 = dot2(th0, vv[2 * j], a0);
        a1 = dot2(th1, vv[2 * j + 1], a1);
        a2 = dot2(th2, vv[2 * j + 2], a2);
        a3 = dot2(th3, vv[2 * j + 3], a3);
      }
      float a = (a0 + a1) + (a2 + a3);
      a += __shfl_xor(a, 1); a += __shfl_xor(a, 2);
      float ea = __expf(a + bV);
      // esc pair store (s, s+1)
      float ep = __shfl_xor(ea, 4);
      if (uq == 0 && !(s & 1)) esc2[s >> 1] = pk2(ea, ep);
      // wave denominator partial: sum distinct s within wave (bits 2..5 of lane)
      float dsum = ea;
      dsum += __shfl_xor(dsum, 4); dsum += __shfl_xor(dsum, 8);
      dsum += __shfl_xor(dsum, 16); dsum += __shfl_xor(dsum, 32);
      if (lane == 0) escw[wid] = dsum;
    }
    {   // z_h partial (independent chain; fills score-phase bubbles)
      int c = tid & 127, kq = tid >> 7;
      const unsigned* whp = &WhU[c * 65 + kq * 16];
      const unsigned* hh2 = &h2[kq * 32];
      float zb0 = 0.f, zb1 = 0.f;
      #pragma unroll
      for (int j = 0; j < 16; ++j) {
        unsigned wh = whp[j];
        zb0 = dot2(e5pair(wh, SEL01), hh2[2 * j], zb0);
        zb1 = dot2(e5pair(wh, SEL23), hh2[2 * j + 1], zb1);
      }
      scr_z[kq * 128 + c] = zb0 + zb1;
    }
    __syncthreads();

    // ---- P3: ctx partials over s-halves ----
    {
      int u = tid & 255, sh = tid >> 8;
      const unsigned* ep = &eoT[u * 33 + sh * 16];
      const unsigned* e2 = &esc2[sh * 32];
      float c0a = 0.f, c1a = 0.f;
      #pragma unroll
      for (int j = 0; j < 16; ++j) {
        unsigned w = ep[j];
        c0a = dot2(e5pair(w, SEL01), e2[2 * j], c0a);
        c1a = dot2(e5pair(w, SEL23), e2[2 * j + 1], c1a);
      }
      scr_c[sh * 256 + u] = c0a + c1a;
    }
    __syncthreads();

    // ---- P4: ctx finalize -> half2 pairs ----
    if (tid < 128) {
      float d = ((escw[0] + escw[1]) + (escw[2] + escw[3])) +
                ((escw[4] + escw[5]) + (escw[6] + escw[7]));
      float dinv = 1.0f / d;
      float ca = (scr_c[2 * tid]     + scr_c[256 + 2 * tid])     * dinv;
      float cb = (scr_c[2 * tid + 1] + scr_c[256 + 2 * tid + 1]) * dinv;
      ctx2[tid] = pk2(ca, cb);
    }
    __syncthreads();

    // ---- P5: z_ctx, accumulate into scr_z ----
    {
      int c = tid & 127, kq = tid >> 7;
      const unsigned* wxp = &WxU[c * 65 + kq * 16];
      const unsigned* cc2 = &ctx2[kq * 32];
      float za0 = 0.f, za1 = 0.f;
      #pragma unroll
      for (int j = 0; j < 16; ++j) {
        unsigned wx = wxp[j];
        za0 = dot2(e5pair(wx, SEL01), cc2[2 * j], za0);
        za1 = dot2(e5pair(wx, SEL23), cc2[2 * j + 1], za1);
      }
      scr_z[kq * 128 + c] += za0 + za1;
    }
    __syncthreads();

    // ---- P6: pointwise LSTM update + h publish ----
    int par1 = (t + 1) & 1;
    unsigned tag2 = (unsigned)(t + 2);
    if (tid < 32) {
      int r = tid, gc = g * 32 + r;
      float zi = scr_z[r]      + scr_z[128 + r]      + scr_z[256 + r]      + scr_z[384 + r]      + xd0;
      float zf = scr_z[32 + r] + scr_z[128 + 32 + r] + scr_z[256 + 32 + r] + scr_z[384 + 32 + r] + xd1;
      float zg = scr_z[64 + r] + scr_z[128 + 64 + r] + scr_z[256 + 64 + r] + scr_z[384 + 64 + r] + xd2;
      float zo = scr_z[96 + r] + scr_z[128 + 96 + r] + scr_z[256 + 96 + r] + scr_z[384 + 96 + r] + xd3;
      float c = sigmoidf_(zf) * c_reg + sigmoidf_(zi) * tanhf_(zg);
      c_reg = c;
      float h = sigmoidf_(zo) * tanhf_(c);
      h_reg = h;
      hsl[r] = h;
      Hbf[(size_t)(t * B_ + b) * U_ + gc] = f2bf(h);
      if (t < T_ - 1) {
        float hx = __shfl_xor(h, 1);
        if (!(r & 1))
          pub64u(&hpub2[((size_t)par1 * 32 + b) * 128 + g * 16 + (r >> 1)], pk2(h, hx), tag2);
      }
    }
    __syncthreads();

    // ---- P7: qpart publish for step t+1 ----
    if (t < T_ - 1 && tid < 256) {
      float qp0 = 0.f, qp1 = 0.f;
      #pragma unroll
      for (int k2 = 0; k2 < 16; k2 += 2) {
        qp0 = dot2(W1L[k2][tid],   pk2(hsl[2*k2],   hsl[2*k2+1]), qp0);
        qp1 = dot2(W1L[k2+1][tid], pk2(hsl[2*k2+2], hsl[2*k2+3]), qp1);
      }
      float qp = qp0 + qp1;
      float qpx = __shfl_xor(qp, 1);
      if (!(tid & 1))
        pub64u(&qp2[(((size_t)par1 * 32 + b) * 128 + (tid >> 1)) * 8 + g], pk2(qp, qpx), tag2);
    }
  }
}

// ---------------------------------------------------------------------------
// K6: fc GEMM (MFMA bf16) + exp epilogue + row-sum partials.
// ---------------------------------------------------------------------------
__global__ __launch_bounds__(256) void k_fc(
    const unsigned short* __restrict__ Hbf, const unsigned short* __restrict__ fcWt,
    const float* __restrict__ fcb, float* __restrict__ out,
    float* __restrict__ rs_part)
{
  __shared__ uint4 Al[128 * 8];
  __shared__ uint4 Bl[128 * 8];
  __shared__ float rsum_l[128][2];

  int bid = blockIdx.x, tid = threadIdx.x;
  int nt = bid >> 5, mt = bid & 31;
  int m0 = mt * 128, n0 = nt * 128;
  int lane = tid & 63, wave = tid >> 6;
  int wm = (wave >> 1) * 64, wn = (wave & 1) * 64;
  int g = lane >> 4, r15 = lane & 15;

  f32x4 acc[4][4];
  f32x4 zero = {0.f, 0.f, 0.f, 0.f};
  #pragma unroll
  for (int mi = 0; mi < 4; ++mi)
    #pragma unroll
    for (int ni = 0; ni < 4; ++ni) acc[mi][ni] = zero;

  const unsigned short* Ag = Hbf  + (size_t)m0 * 256;
  const unsigned short* Bg = fcWt + (size_t)n0 * 256;

  for (int kt = 0; kt < 4; ++kt) {
    int kk = kt * 64;
    #pragma unroll
    for (int blk = 0; blk < 4; ++blk) {
      int lin = blk * 256 + tid;
      int row = lin >> 3, kq = lin & 7;
      Al[row * 8 + (kq ^ (row & 7))] = *(const uint4*)(Ag + (size_t)row * 256 + kk + kq * 8);
      Bl[row * 8 + (kq ^ (row & 7))] = *(const uint4*)(Bg + (size_t)row * 256 + kk + kq * 8);
    }
    __syncthreads();
    #pragma unroll
    for (int kk2 = 0; kk2 < 2; ++kk2) {
      short8_t a[4], bfr[4];
      #pragma unroll
      for (int mi = 0; mi < 4; ++mi) {
        int row = wm + mi * 16 + r15;
        a[mi] = *(const short8_t*)&Al[row * 8 + ((kk2 * 4 + g) ^ (row & 7))];
      }
      #pragma unroll
      for (int ni = 0; ni < 4; ++ni) {
        int row = wn + ni * 16 + r15;
        bfr[ni] = *(const short8_t*)&Bl[row * 8 + ((kk2 * 4 + g) ^ (row & 7))];
      }
      #pragma unroll
      for (int mi = 0; mi < 4; ++mi)
        #pragma unroll
        for (int ni = 0; ni < 4; ++ni)
          acc[mi][ni] = __builtin_amdgcn_mfma_f32_16x16x32_bf16(a[mi], bfr[ni], acc[mi][ni], 0, 0, 0);
    }
    __syncthreads();
  }

  float fcb_l[4];
  #pragma unroll
  for (int ni = 0; ni < 4; ++ni) fcb_l[ni] = fcb[n0 + wn + ni * 16 + r15];

  #pragma unroll
  for (int mi = 0; mi < 4; ++mi) {
    #pragma unroll
    for (int jj = 0; jj < 4; ++jj) {
      int rloc = wm + mi * 16 + g * 4 + jj;
      int grow = m0 + rloc;                     // = t*32 + b
      int bb = grow & 31, tt = grow >> 5;
      size_t obase = (size_t)bb * TV + (size_t)tt * V_;
      float s = 0.f;
      #pragma unroll
      for (int ni = 0; ni < 4; ++ni) {
        float v = __expf(acc[mi][ni][jj] + fcb_l[ni]);
        out[obase + n0 + wn + ni * 16 + r15] = v;
        s += v;
      }
      s += __shfl_xor(s, 1); s += __shfl_xor(s, 2);
      s += __shfl_xor(s, 4); s += __shfl_xor(s, 8);
      if (r15 == 0) rsum_l[rloc][wave & 1] = s;
    }
  }
  __syncthreads();
  if (tid < 128)
    rs_part[(size_t)nt * 4096 + m0 + tid] = rsum_l[tid][0] + rsum_l[tid][1];
}

// ---------------------------------------------------------------------------
// K7: reduce partial row sums -> 1/sum per GEMM row
// ---------------------------------------------------------------------------
__global__ __launch_bounds__(256) void k_rowsum(
    const float* __restrict__ rs_part, float* __restrict__ row_inv)
{
  int gidx = blockIdx.x * 256 + threadIdx.x;
  float s = 0.f;
  for (int nt = 0; nt < 250; ++nt) s += rs_part[(size_t)nt * 4096 + gidx];
  row_inv[gidx] = 1.0f / s;
}

// ---------------------------------------------------------------------------
// K8: normalize probs in place
// ---------------------------------------------------------------------------
__global__ __launch_bounds__(256) void k_norm(
    float4* __restrict__ out4, const float* __restrict__ row_inv)
{
  const long total = 32768000;
  long stride = (long)gridDim.x * 256;
  for (long i = (long)blockIdx.x * 256 + threadIdx.x; i < total; i += stride) {
    long flat = i * 4;
    int bb = (int)(flat / TV);
    int rem = (int)(flat % TV);
    int tt = rem / V_;
    float sc = row_inv[tt * 32 + bb];
    float4 v = out4[i];
    v.x *= sc; v.y *= sc; v.z *= sc; v.w *= sc;
    out4[i] = v;
  }
}

// ---------------------------------------------------------------------------
extern "C" void kernel_launch(void* const* d_in, const int* in_sizes, int n_in,
                              void* d_out, int out_size, void* d_ws, size_t ws_size,
                              hipStream_t stream) {
  (void)in_sizes; (void)n_in; (void)out_size; (void)ws_size;
  const int*   src     = (const int*)d_in[0];
  const int*   tgt     = (const int*)d_in[1];
  const float* enc_emb = (const float*)d_in[2];
  const float* enc_Wx  = (const float*)d_in[3];
  const float* enc_Wh  = (const float*)d_in[4];
  const float* enc_b   = (const float*)d_in[5];
  const float* dec_emb = (const float*)d_in[6];
  const float* dec_Wx  = (const float*)d_in[7];
  const float* dec_Wh  = (const float*)d_in[8];
  const float* dec_b   = (const float*)d_in[9];
  const float* att_W1  = (const float*)d_in[10];
  const float* att_b1  = (const float*)d_in[11];
  const float* att_W2  = (const float*)d_in[12];
  const float* att_b2  = (const float*)d_in[13];
  const float* att_V   = (const float*)d_in[14];
  const float* att_bV  = (const float*)d_in[15];
  const float* fc_W    = (const float*)d_in[16];
  const float* fc_b    = (const float*)d_in[17];
  float* out = (float*)d_out;

  char* ws = (char*)d_ws;
  size_t o = 0;
  auto alloc = [&](size_t bytes) {
    char* p = ws + o;
    o = (o + bytes + 255) & ~(size_t)255;
    return p;
  };
  float*          Xe      = (float*)alloc((size_t)S_ * B_ * G4 * 4);
  float*          Xd      = (float*)alloc((size_t)T_ * B_ * G4 * 4);
  float*          enc_out = (float*)alloc((size_t)B_ * S_ * U_ * 4);
  float*          keys    = (float*)alloc((size_t)B_ * S_ * U_ * 4);
  unsigned short* Hbf     = (unsigned short*)alloc((size_t)T_ * B_ * U_ * 2);
  unsigned short* fcWt    = (unsigned short*)alloc((size_t)V_ * U_ * 2);
  float*          h_state = (float*)alloc((size_t)B_ * U_ * 4);
  float*          c_state = (float*)alloc((size_t)B_ * U_ * 4);
  float*          rs_part = (float*)alloc((size_t)250 * 4096 * 4);
  float*          row_inv = (float*)alloc((size_t)4096 * 4);
  // tagged publication buffers (zeroed each launch for graph replay)
  size_t pub_off = o;
  u64* hpubE = (u64*)alloc((size_t)2 * 32 * 256 * 8);
  u64* hpub2 = (u64*)alloc((size_t)2 * 32 * 128 * 8);
  u64* qp2   = (u64*)alloc((size_t)2 * 32 * 128 * 8 * 8);
  size_t pub_bytes = o - pub_off;

  hipMemsetAsync(ws + pub_off, 0, pub_bytes, stream);
  hipLaunchKernelGGL(k_prep_x, dim3(1024), dim3(256), 0, stream,
                     src, tgt, enc_emb, enc_Wx, enc_b, dec_emb, dec_Wx, dec_b, Xe, Xd);
  hipLaunchKernelGGL(k_prep_fcw, dim3(2000), dim3(256), 0, stream, fc_W, fcWt);
  hipLaunchKernelGGL(k_encoder8, dim3(256), dim3(256), 0, stream,
                     Xe, enc_Wh, enc_out, h_state, c_state, hpubE);
  hipLaunchKernelGGL(k_keys, dim3(512), dim3(256), 0, stream,
                     enc_out, att_W2, att_b2, keys);
  hipLaunchKernelGGL(k_decoder8, dim3(256), dim3(512), 0, stream,
                     Xd, dec_Wx, dec_Wh, att_W1, att_b1, att_V, att_bV,
                     enc_out, keys, h_state, c_state, Hbf,
                     hpub2, qp2);
  hipLaunchKernelGGL(k_fc, dim3(8000), dim3(256), 0, stream,
                     Hbf, fcWt, fc_b, out, rs_part);
  hipLaunchKernelGGL(k_rowsum, dim3(16), dim3(256), 0, stream, rs_part, row_inv);
  hipLaunchKernelGGL(k_norm, dim3(2048), dim3(256), 0, stream,
                     (float4*)d_out, row_inv);
}